// Round 2
// baseline (1865.124 us; speedup 1.0000x reference)
//
#include <hip/hip_runtime.h>
#include <hip/hip_bf16.h>

#define EPS       0.05f
#define N_ITERS   20
#define NR        8192      // N == M
#define DIM       64
#define LOG2E     1.4426950408889634f
#define LN2       0.6931471805599453f
#define S2        (2.0f * LOG2E / EPS)   // folded into xs at prep
#define EPSLN2    (EPS * LN2)
#define NEGINF    (-1e30f)
#define NSPLIT    16                     // column splits (partials per side)
#define NPASS     (2 * N_ITERS + 2)      // 40 sinkhorn + 2 final passes

typedef __attribute__((ext_vector_type(8))) short short8;
typedef __attribute__((ext_vector_type(4))) float float4v;

#define GLD_LDS16(src, dst)                                              \
    __builtin_amdgcn_global_load_lds(                                    \
        (const __attribute__((address_space(1))) void*)(src),            \
        (__attribute__((address_space(3))) void*)(dst), 16, 0, 0)

__device__ __forceinline__ float wave_reduce_sum(float v) {
    #pragma unroll
    for (int m = 1; m < 64; m <<= 1) v += __shfl_xor(v, m, 64);
    return v;
}

// merged log2-LSE of NSPLIT partials for row/col i
__device__ __forceinline__ float merge16_l(const float2* P, int i) {
    float2 p[NSPLIT];
    float M = NEGINF;
    #pragma unroll
    for (int k = 0; k < NSPLIT; k++) {
        p[k] = P[k * NR + i];
        M = fmaxf(M, p[k].x);
    }
    float S = 0.f;
    #pragma unroll
    for (int k = 0; k < NSPLIT; k++)
        S += p[k].y * __builtin_amdgcn_exp2f(p[k].x - M);
    return M + __builtin_amdgcn_logf(S);   // log2 domain
}

// ---- grid-wide sync: agent-scope atomics + release/acquire fences ----------
// sv[0] = arrival counter, sv[1] = generation. Zeroed by sums_kernel each call.
__device__ __forceinline__ void gsync(unsigned* sv) {
    __syncthreads();
    if (threadIdx.x == 0) {
        __threadfence();                                   // release my writes
        unsigned g = __hip_atomic_load(&sv[1], __ATOMIC_RELAXED,
                                       __HIP_MEMORY_SCOPE_AGENT);
        unsigned a = __hip_atomic_fetch_add(&sv[0], 1u, __ATOMIC_ACQ_REL,
                                            __HIP_MEMORY_SCOPE_AGENT);
        if (a == 255u) {                                   // last arriver
            __hip_atomic_store(&sv[0], 0u, __ATOMIC_RELAXED,
                               __HIP_MEMORY_SCOPE_AGENT);
            __hip_atomic_store(&sv[1], g + 1u, __ATOMIC_RELEASE,
                               __HIP_MEMORY_SCOPE_AGENT);
        } else {
            while (__hip_atomic_load(&sv[1], __ATOMIC_RELAXED,
                                     __HIP_MEMORY_SCOPE_AGENT) == g)
                __builtin_amdgcn_s_sleep(1);
        }
        __threadfence();                                   // acquire (L1/L2 inv)
    }
    __syncthreads();
}

// ---- setup: sums of a and b + zero the grid-sync slots ---------------------
__global__ void sums_kernel(const float* __restrict__ a, const float* __restrict__ b,
                            float* __restrict__ sums, unsigned* __restrict__ sv) {
    __shared__ float red[32];
    int tid = threadIdx.x;
    float pa = 0.f, pb = 0.f;
    for (int i = tid; i < NR; i += blockDim.x) { pa += a[i]; pb += b[i]; }
    pa = wave_reduce_sum(pa);
    pb = wave_reduce_sum(pb);
    int wid = tid >> 6, ln = tid & 63;
    if (ln == 0) { red[wid] = pa; red[wid + 16] = pb; }
    __syncthreads();
    if (tid == 0) {
        float sa = 0.f, sb = 0.f;
        int nw = blockDim.x >> 6;
        for (int w = 0; w < nw; w++) { sa += red[w]; sb += red[w + 16]; }
        sums[0] = logf(sa); sums[1] = logf(sb); sums[2] = sa; sums[3] = sb;
        sv[0] = 0u; sv[1] = 0u;
    }
}

// ---- setup: bf16 stream-layout copies, norms, weights, initial partials ----
// xs pre-scaled by S2 so MFMA output is z directly (bias enters as C-operand).
__global__ void prep_kernel(const float* __restrict__ x, const float* __restrict__ y,
                            const float* __restrict__ a, const float* __restrict__ b,
                            const float* __restrict__ sums,
                            short8* __restrict__ xs, short8* __restrict__ ys,
                            float* __restrict__ x2, float* __restrict__ y2,
                            float* __restrict__ la2, float* __restrict__ lb2,
                            float2* __restrict__ Pb) {   // [NSPLIT][NR] g-partials
    int gid = blockIdx.x * 256 + threadIdx.x;
    bool isx = gid < NR * 8;
    int cid = isx ? gid : gid - NR * 8;
    int row = cid >> 3;
    int c   = cid & 7;
    const float4* src = (const float4*)(isx ? x : y);
    float4 v0 = src[row * 16 + c * 2];
    float4 v1 = src[row * 16 + c * 2 + 1];

    const float sc = isx ? S2 : 1.0f;
    short8 st;
    st[0] = __bfloat16_as_short(__float2bfloat16(v0.x * sc));
    st[1] = __bfloat16_as_short(__float2bfloat16(v0.y * sc));
    st[2] = __bfloat16_as_short(__float2bfloat16(v0.z * sc));
    st[3] = __bfloat16_as_short(__float2bfloat16(v0.w * sc));
    st[4] = __bfloat16_as_short(__float2bfloat16(v1.x * sc));
    st[5] = __bfloat16_as_short(__float2bfloat16(v1.y * sc));
    st[6] = __bfloat16_as_short(__float2bfloat16(v1.z * sc));
    st[7] = __bfloat16_as_short(__float2bfloat16(v1.w * sc));

    int T = row >> 4, ln = row & 15, f = c >> 2, q = c & 3;
    (isx ? xs : ys)[T * 128 + f * 64 + q * 16 + ln] = st;    // stream layout

    float sq = v0.x*v0.x + v0.y*v0.y + v0.z*v0.z + v0.w*v0.w
             + v1.x*v1.x + v1.y*v1.y + v1.z*v1.z + v1.w*v1.w;
    #pragma unroll
    for (int m = 1; m < 8; m <<= 1) sq += __shfl_xor(sq, m, 64);

    if (c == 0) {
        if (isx) {
            x2[row] = sq;
            la2[row] = (logf(a[row]) - sums[0]) * LOG2E;
        } else {
            y2[row] = sq;
            lb2[row] = (logf(b[row]) - sums[1]) * LOG2E;
            Pb[row] = make_float2(sq * (LOG2E / EPS), 1.0f);   // g = 0 initially
            #pragma unroll
            for (int k = 1; k < NSPLIT; k++)
                Pb[k * NR + row] = make_float2(NEGINF, 0.0f);
        }
    }
}

// acc already IS z (bias folded into MFMA C-operand, S2 folded into data).
#define LSE4(acc, mm, ss)                                                \
    {                                                                    \
        float z0 = (acc)[0], z1 = (acc)[1];                              \
        float z2 = (acc)[2], z3 = (acc)[3];                              \
        float mn = fmaxf(fmaxf(fmaxf(z0, z1), fmaxf(z2, z3)), (mm));     \
        float e  = __builtin_amdgcn_exp2f((mm) - mn);                    \
        float p  = (__builtin_amdgcn_exp2f(z0 - mn)                      \
                  + __builtin_amdgcn_exp2f(z1 - mn))                     \
                 + (__builtin_amdgcn_exp2f(z2 - mn)                      \
                  + __builtin_amdgcn_exp2f(z3 - mn));                    \
        (ss) = fmaf((ss), e, p);                                         \
        (mm) = mn;                                                       \
    }

// ---- persistent cooperative kernel: all 42 passes + reduction --------------
// Block (i = b>>4, j = b&15) permanently holds X-slice i (64K) and Y-slice j
// (64K) in LDS — staged ONCE. f-pass: rows=X_i, cols=Y_j -> Pf[j][512i..].
// g-pass: rows=Y_j, cols=X_i -> Pb[i][512j..]. Grid sync between passes.
// Waves: rq = w>>1 (64-row eighth, 4 tiles in regs), cst = w&1 (256-col half).
// LDS: 128K mats + 2K cbl + 12K comb = 142 KB -> 1 block/CU, grid 256 = CUs.
__global__ __launch_bounds__(1024, 4) void sink_kernel(
        const short8* __restrict__ xs, const short8* __restrict__ ys,
        const float* __restrict__ la2, const float* __restrict__ lb2,
        float2* P,                       // Pf | Pb | Pff | Pgf (no restrict!)
        const float* __restrict__ a, const float* __restrict__ b,
        const float* __restrict__ x2, const float* __restrict__ y2,
        float2* red2, const float* __restrict__ sums,
        unsigned* sv, float* out) {
    __shared__ __attribute__((aligned(16))) char mlds[131072];  // X | Y
    __shared__ __attribute__((aligned(16))) float cbl[512];
    __shared__ float2 comb[512][3];      // [row][strip] (+1 pad)

    const int tid = threadIdx.x;
    const int bi  = blockIdx.x;
    const int ib  = bi >> 4, jb = bi & 15;
    const int w   = tid >> 6, lane = tid & 63;
    const int quad = lane >> 4, ln = lane & 15;
    const int cst = w & 1, rq = w >> 1;

    float2* Pf  = P;
    float2* Pb  = P + NSPLIT * NR;
    float2* Pff = P + 2 * NSPLIT * NR;
    float2* Pgf = P + 3 * NSPLIT * NR;

    // ---- stage both slices ONCE (128 KB) ----
    const char* xsrc = (const char*)xs + (size_t)(ib * 512) * 128;
    const char* ysrc = (const char*)ys + (size_t)(jb * 512) * 128;
    #pragma unroll
    for (int r = 0; r < 4; r++) {
        GLD_LDS16(xsrc + r * 16384 + tid * 16, &mlds[r * 16384 + w * 1024]);
        GLD_LDS16(ysrc + r * 16384 + tid * 16, &mlds[65536 + r * 16384 + w * 1024]);
    }

    for (int p = 0; p < NPASS; p++) {
        const bool fs = (p < 2 * N_ITERS) ? !(p & 1) : (p == 2 * N_ITERS);
        const float2* Pin = fs ? Pb : Pf;
        float2* Pout = fs ? (p == 2 * N_ITERS     ? Pff : Pf)
                          : (p == 2 * N_ITERS + 1 ? Pgf : Pb);
        const float* lw  = fs ? lb2 : la2;
        const int colbase = 512 * (fs ? jb : ib);
        const int outidx  = fs ? (jb * NR + 512 * ib) : (ib * NR + 512 * jb);
        const int roff = fs ? 0 : 65536;          // rows slice in mlds
        const int coff = fs ? 65536 : 0;          // cols slice in mlds

        // ---- prologue: merge 16 column partials -> cbl ----
        if (tid < 512) {
            int jj = colbase + tid;
            cbl[tid] = lw[jj] - merge16_l(Pin, jj);
        }
        __syncthreads();   // cbl ready (p==0: staging vmcnt drained here too)

        // ---- row fragments from LDS: 4 tiles (rows rq*64 + t*16 + ln) ----
        short8 rf0[4], rf1[4];
        {
            const char* rw = &mlds[roff + rq * 8192];
            #pragma unroll
            for (int t = 0; t < 4; t++) {
                rf0[t] = *(const short8*)(rw + t * 2048 + lane * 16);
                rf1[t] = *(const short8*)(rw + t * 2048 + 1024 + lane * 16);
            }
        }

        float lm[4], ls[4];
        #pragma unroll
        for (int t = 0; t < 4; t++) { lm[t] = NEGINF; ls[t] = 0.f; }

        const char* cw = &mlds[coff + cst * 32768];
        const float* cbw = cbl + cst * 256;
        #pragma unroll 4
        for (int u = 0; u < 16; u++) {
            short8 ya0 = *(const short8*)(cw + u * 2048 + lane * 16);
            short8 ya1 = *(const short8*)(cw + u * 2048 + 1024 + lane * 16);
            float4v cin = *(const float4v*)(cbw + u * 16 + quad * 4);
            #pragma unroll
            for (int tt = 0; tt < 4; tt++) {
                float4v acc = __builtin_amdgcn_mfma_f32_16x16x32_bf16(ya0, rf0[tt], cin, 0, 0, 0);
                acc = __builtin_amdgcn_mfma_f32_16x16x32_bf16(ya1, rf1[tt], acc, 0, 0, 0);
                LSE4(acc, lm[tt], ls[tt]);
            }
        }

        // combine across the 4 quads (same ln = same output rows)
        #pragma unroll
        for (int mask = 16; mask < 64; mask <<= 1) {
            #pragma unroll
            for (int t = 0; t < 4; t++) {
                float mo = __shfl_xor(lm[t], mask, 64);
                float so = __shfl_xor(ls[t], mask, 64);
                float M  = fmaxf(lm[t], mo);
                ls[t] = ls[t] * __builtin_amdgcn_exp2f(lm[t] - M)
                      + so    * __builtin_amdgcn_exp2f(mo    - M);
                lm[t] = M;
            }
        }

        if (lane < 16) {
            #pragma unroll
            for (int t = 0; t < 4; t++)
                comb[rq * 64 + t * 16 + ln][cst] = make_float2(lm[t], ls[t]);
        }
        __syncthreads();

        // merge the 2 strips per row; write this split's partial
        if (tid < 512) {
            float2 c0 = comb[tid][0], c1 = comb[tid][1];
            float M = fmaxf(c0.x, c1.x);
            float S = c0.y * __builtin_amdgcn_exp2f(c0.x - M)
                    + c1.y * __builtin_amdgcn_exp2f(c1.x - M);
            Pout[outidx + tid] = make_float2(M, S);
        }
        gsync(sv);
    }

    // ---- reduction stage 1: blocks 0..63, threads 0..255 ----
    if (bi < 64 && tid < 256) {
        int r = bi * 128 + (tid & 127);
        bool gsd = tid >= 128;                 // 0-127: f side, 128-255: g side
        float L  = merge16_l(gsd ? Pgf : Pff, r);
        float sq = gsd ? y2[r] : x2[r];
        float wv = gsd ? b[r]  : a[r];
        float v  = wv * (sq - EPSLN2 * L);
        v = wave_reduce_sum(v);
        if ((tid & 63) == 0) cbl[tid >> 6] = v;
    }
    __syncthreads();
    if (bi < 64 && tid == 0)
        red2[bi] = make_float2(cbl[0] + cbl[1], cbl[2] + cbl[3]);
    gsync(sv);

    // ---- reduction stage 2: block 0, one wave ----
    if (bi == 0 && tid < 64) {
        float2 v = red2[tid];
        float da = wave_reduce_sum(v.x);
        float db = wave_reduce_sum(v.y);
        if (tid == 0) out[0] = da / sums[2] + db / sums[3];
    }
}

extern "C" void kernel_launch(void* const* d_in, const int* in_sizes, int n_in,
                              void* d_out, int out_size, void* d_ws, size_t ws_size,
                              hipStream_t stream) {
    const float* a = (const float*)d_in[0];
    const float* x = (const float*)d_in[1];
    const float* b = (const float*)d_in[2];
    const float* y = (const float*)d_in[3];

    char* ws = (char*)d_ws;
    short8* xs = (short8*)ws;                        // 1 MB stream layout
    short8* ys = (short8*)(ws + (1 << 20));          // 1 MB
    float* fp  = (float*)(ws + (2 << 20));
    float* x2  = fp;
    float* y2  = fp + NR;
    float* la2 = fp + 2 * NR;
    float* lb2 = fp + 3 * NR;
    float2* P   = (float2*)(fp + 4 * NR);            // Pf|Pb|Pff|Pgf, 4 MB
    float2* red2 = P + 4 * NSPLIT * NR;              // 64 entries
    float* sums  = (float*)(red2 + 64);              // 4 floats
    unsigned* sv = (unsigned*)(sums + 4);            // 2 grid-sync slots
    float* outp  = (float*)d_out;

    sums_kernel<<<1, 1024, 0, stream>>>(a, b, sums, sv);
    prep_kernel<<<(2 * NR * 8) / 256, 256, 0, stream>>>(x, y, a, b, sums,
                                                        xs, ys,
                                                        x2, y2, la2, lb2,
                                                        P + NSPLIT * NR);

    void* args[] = { (void*)&xs, (void*)&ys, (void*)&la2, (void*)&lb2,
                     (void*)&P, (void*)&a, (void*)&b, (void*)&x2, (void*)&y2,
                     (void*)&red2, (void*)&sums, (void*)&sv, (void*)&outp };
    hipLaunchCooperativeKernel((void*)sink_kernel, dim3(256), dim3(1024),
                               args, 0, stream);
}

// Round 4
// 1544.638 us; speedup vs baseline: 1.2075x; 1.2075x over previous
//
#include <hip/hip_runtime.h>
#include <hip/hip_bf16.h>

#define EPS       0.05f
#define N_ITERS   20
#define NR        8192      // N == M
#define DIM       64
#define LOG2E     1.4426950408889634f
#define LN2       0.6931471805599453f
#define S2        (2.0f * LOG2E / EPS)   // folded into xs at prep
#define EPSLN2    (EPS * LN2)
#define NEGINF    (-1e30f)
#define NSPLIT    16                     // column splits (partials per side)
#define PSZ       (NSPLIT * NR)          // one partial array (float2 count)

typedef __attribute__((ext_vector_type(8))) short short8;
typedef __attribute__((ext_vector_type(4))) float float4v;

#define GLD_LDS16(src, dst)                                              \
    __builtin_amdgcn_global_load_lds(                                    \
        (const __attribute__((address_space(1))) void*)(src),            \
        (__attribute__((address_space(3))) void*)(dst), 16, 0, 0)

__device__ __forceinline__ float wave_reduce_sum(float v) {
    #pragma unroll
    for (int m = 1; m < 64; m <<= 1) v += __shfl_xor(v, m, 64);
    return v;
}

// merged log2-LSE of NSPLIT partials for row/col i
__device__ __forceinline__ float merge16_l(const float2* P, int i) {
    float2 p[NSPLIT];
    float M = NEGINF;
    #pragma unroll
    for (int k = 0; k < NSPLIT; k++) {
        p[k] = P[k * NR + i];
        M = fmaxf(M, p[k].x);
    }
    float S = 0.f;
    #pragma unroll
    for (int k = 0; k < NSPLIT; k++)
        S += p[k].y * __builtin_amdgcn_exp2f(p[k].x - M);
    return M + __builtin_amdgcn_logf(S);   // log2 domain
}

// ---- n-block barrier: EXACT R13 gsync primitive (proven on HW), n-party ----
// bar[0] = arrival counter, bar[1] = generation; one 128B line per group.
__device__ __forceinline__ void gsync_n(unsigned* bar, unsigned n) {
    __syncthreads();
    if (threadIdx.x == 0) {
        __threadfence();                                   // release my writes
        unsigned g = __hip_atomic_load(&bar[1], __ATOMIC_RELAXED,
                                       __HIP_MEMORY_SCOPE_AGENT);
        unsigned a = __hip_atomic_fetch_add(&bar[0], 1u, __ATOMIC_ACQ_REL,
                                            __HIP_MEMORY_SCOPE_AGENT);
        if (a == n - 1u) {                                 // last arriver
            __hip_atomic_store(&bar[0], 0u, __ATOMIC_RELAXED,
                               __HIP_MEMORY_SCOPE_AGENT);
            __hip_atomic_store(&bar[1], g + 1u, __ATOMIC_RELEASE,
                               __HIP_MEMORY_SCOPE_AGENT);
        } else {
            while (__hip_atomic_load(&bar[1], __ATOMIC_RELAXED,
                                     __HIP_MEMORY_SCOPE_AGENT) == g)
                __builtin_amdgcn_s_sleep(1);
        }
        __threadfence();                                   // acquire
    }
    __syncthreads();
}

// ---- setup: sums of a and b + zero all barrier lines -----------------------
__global__ void sums_kernel(const float* __restrict__ a, const float* __restrict__ b,
                            float* __restrict__ sums, unsigned* __restrict__ barr) {
    __shared__ float red[32];
    int tid = threadIdx.x;
    if (tid < 1024) barr[tid] = 0u;        // 32 groups x 32 u32 lines
    float pa = 0.f, pb = 0.f;
    for (int i = tid; i < NR; i += blockDim.x) { pa += a[i]; pb += b[i]; }
    pa = wave_reduce_sum(pa);
    pb = wave_reduce_sum(pb);
    int wid = tid >> 6, ln = tid & 63;
    if (ln == 0) { red[wid] = pa; red[wid + 16] = pb; }
    __syncthreads();
    if (tid == 0) {
        float sa = 0.f, sb = 0.f;
        int nw = blockDim.x >> 6;
        for (int w = 0; w < nw; w++) { sa += red[w]; sb += red[w + 16]; }
        sums[0] = logf(sa); sums[1] = logf(sb); sums[2] = sa; sums[3] = sb;
    }
}

// ---- setup: bf16 stream-layout copies, norms, weights, initial partials ----
// xs pre-scaled by S2 so MFMA output is z directly (bias enters as C-operand).
__global__ void prep_kernel(const float* __restrict__ x, const float* __restrict__ y,
                            const float* __restrict__ a, const float* __restrict__ b,
                            const float* __restrict__ sums,
                            short8* __restrict__ xs, short8* __restrict__ ys,
                            float* __restrict__ x2, float* __restrict__ y2,
                            float* __restrict__ la2, float* __restrict__ lb2,
                            float2* __restrict__ Pb1) {  // initial g-partials
    int gid = blockIdx.x * 256 + threadIdx.x;
    bool isx = gid < NR * 8;
    int cid = isx ? gid : gid - NR * 8;
    int row = cid >> 3;
    int c   = cid & 7;
    const float4* src = (const float4*)(isx ? x : y);
    float4 v0 = src[row * 16 + c * 2];
    float4 v1 = src[row * 16 + c * 2 + 1];

    const float sc = isx ? S2 : 1.0f;
    short8 st;
    st[0] = __bfloat16_as_short(__float2bfloat16(v0.x * sc));
    st[1] = __bfloat16_as_short(__float2bfloat16(v0.y * sc));
    st[2] = __bfloat16_as_short(__float2bfloat16(v0.z * sc));
    st[3] = __bfloat16_as_short(__float2bfloat16(v0.w * sc));
    st[4] = __bfloat16_as_short(__float2bfloat16(v1.x * sc));
    st[5] = __bfloat16_as_short(__float2bfloat16(v1.y * sc));
    st[6] = __bfloat16_as_short(__float2bfloat16(v1.z * sc));
    st[7] = __bfloat16_as_short(__float2bfloat16(v1.w * sc));

    int T = row >> 4, ln = row & 15, f = c >> 2, q = c & 3;
    (isx ? xs : ys)[T * 128 + f * 64 + q * 16 + ln] = st;    // stream layout

    float sq = v0.x*v0.x + v0.y*v0.y + v0.z*v0.z + v0.w*v0.w
             + v1.x*v1.x + v1.y*v1.y + v1.z*v1.z + v1.w*v1.w;
    #pragma unroll
    for (int m = 1; m < 8; m <<= 1) sq += __shfl_xor(sq, m, 64);

    if (c == 0) {
        if (isx) {
            x2[row] = sq;
            la2[row] = (logf(a[row]) - sums[0]) * LOG2E;
        } else {
            y2[row] = sq;
            lb2[row] = (logf(b[row]) - sums[1]) * LOG2E;
            Pb1[row] = make_float2(sq * (LOG2E / EPS), 1.0f);  // g = 0 initially
            #pragma unroll
            for (int k = 1; k < NSPLIT; k++)
                Pb1[k * NR + row] = make_float2(NEGINF, 0.0f);
        }
    }
}

// acc already IS z (bias folded into MFMA C-operand, S2 folded into data).
#define LSE4(acc, mm, ss)                                                \
    {                                                                    \
        float z0 = (acc)[0], z1 = (acc)[1];                              \
        float z2 = (acc)[2], z3 = (acc)[3];                              \
        float mn = fmaxf(fmaxf(fmaxf(z0, z1), fmaxf(z2, z3)), (mm));     \
        float e  = __builtin_amdgcn_exp2f((mm) - mn);                    \
        float p  = (__builtin_amdgcn_exp2f(z0 - mn)                      \
                  + __builtin_amdgcn_exp2f(z1 - mn))                     \
                 + (__builtin_amdgcn_exp2f(z2 - mn)                      \
                  + __builtin_amdgcn_exp2f(z3 - mn));                    \
        (ss) = fmaf((ss), e, p);                                         \
        (mm) = mn;                                                       \
    }

// ---- one softmin pass over the block's resident 512x512 tile ---------------
__device__ __forceinline__ void do_pass(
        const float2* Pin, const float* lw, float2* Pout,
        int colbase, int outidx, int roff, int coff,
        char* mlds, float* cbl, float2 (*comb)[3]) {
    const int tid = threadIdx.x;
    const int w   = tid >> 6, lane = tid & 63;
    const int quad = lane >> 4, ln = lane & 15;
    const int cst = w & 1, rq = w >> 1;

    // prologue: merge 16 column partials -> cbl
    if (tid < 512) {
        int jj = colbase + tid;
        cbl[tid] = lw[jj] - merge16_l(Pin, jj);
    }
    __syncthreads();

    // row fragments from LDS: 4 tiles (rows rq*64 + t*16 + ln)
    short8 rf0[4], rf1[4];
    {
        const char* rw = &mlds[roff + rq * 8192];
        #pragma unroll
        for (int t = 0; t < 4; t++) {
            rf0[t] = *(const short8*)(rw + t * 2048 + lane * 16);
            rf1[t] = *(const short8*)(rw + t * 2048 + 1024 + lane * 16);
        }
    }

    float lm[4], ls[4];
    #pragma unroll
    for (int t = 0; t < 4; t++) { lm[t] = NEGINF; ls[t] = 0.f; }

    const char* cw = &mlds[coff + cst * 32768];
    const float* cbw = cbl + cst * 256;
    #pragma unroll 4
    for (int u = 0; u < 16; u++) {
        short8 ya0 = *(const short8*)(cw + u * 2048 + lane * 16);
        short8 ya1 = *(const short8*)(cw + u * 2048 + 1024 + lane * 16);
        float4v cin = *(const float4v*)(cbw + u * 16 + quad * 4);
        #pragma unroll
        for (int tt = 0; tt < 4; tt++) {
            float4v acc = __builtin_amdgcn_mfma_f32_16x16x32_bf16(ya0, rf0[tt], cin, 0, 0, 0);
            acc = __builtin_amdgcn_mfma_f32_16x16x32_bf16(ya1, rf1[tt], acc, 0, 0, 0);
            LSE4(acc, lm[tt], ls[tt]);
        }
    }

    // combine across the 4 quads (same ln = same output rows)
    #pragma unroll
    for (int mask = 16; mask < 64; mask <<= 1) {
        #pragma unroll
        for (int t = 0; t < 4; t++) {
            float mo = __shfl_xor(lm[t], mask, 64);
            float so = __shfl_xor(ls[t], mask, 64);
            float M  = fmaxf(lm[t], mo);
            ls[t] = ls[t] * __builtin_amdgcn_exp2f(lm[t] - M)
                  + so    * __builtin_amdgcn_exp2f(mo    - M);
            lm[t] = M;
        }
    }

    __syncthreads();   // comb reuse safe across passes
    if (lane < 16) {
        #pragma unroll
        for (int t = 0; t < 4; t++)
            comb[rq * 64 + t * 16 + ln][cst] = make_float2(lm[t], ls[t]);
    }
    __syncthreads();

    // merge the 2 strips per row; write this split's partial
    if (tid < 512) {
        float2 c0 = comb[tid][0], c1 = comb[tid][1];
        float M = fmaxf(c0.x, c1.x);
        float S = c0.y * __builtin_amdgcn_exp2f(c0.x - M)
                + c1.y * __builtin_amdgcn_exp2f(c1.x - M);
        Pout[outidx + tid] = make_float2(M, S);
    }
}

// ---- persistent cooperative kernel: all 42 passes + reduction --------------
// Block (i,j) holds X-slice i and Y-slice j in LDS, staged ONCE.
// f-pass writes Pf[par][j][512i] (readers: row-group i) -> row-group barrier.
// g-pass writes Pb[par][i][512j] (readers: col-group j) -> col-group barrier.
// Pf/Pb double-buffered by parity (WAR-safe under the group barriers).
// Finals alias Pff=Pf[0], Pgf=Pb[0] (dead after iter 19 — verified).
// Grid-wide sync = row-bar then col-bar (butterfly: transitively all 256).
__global__ __launch_bounds__(1024, 4) void sink_kernel(
        const short8* __restrict__ xs, const short8* __restrict__ ys,
        const float* __restrict__ la2, const float* __restrict__ lb2,
        float2* P,                       // Pf0|Pf1|Pb0|Pb1 (no restrict)
        const float* __restrict__ a, const float* __restrict__ b,
        const float* __restrict__ x2, const float* __restrict__ y2,
        float2* red2, const float* __restrict__ sums,
        unsigned* barr, float* out) {
    __shared__ __attribute__((aligned(16))) char mlds[131072];  // X | Y
    __shared__ __attribute__((aligned(16))) float cbl[512];
    __shared__ float2 comb[512][3];      // [row][strip] (+1 pad)

    const int tid = threadIdx.x;
    const int bi  = blockIdx.x;
    const int ib  = bi >> 4, jb = bi & 15;

    float2* Pf[2] = { P,           P + PSZ };
    float2* Pb[2] = { P + 2 * PSZ, P + 3 * PSZ };
    float2* Pff   = P;                   // alias Pf[0] (safe, see header)
    float2* Pgf   = P + 2 * PSZ;         // alias Pb[0]
    unsigned* rbar = barr + ib * 32;         // row-group i line
    unsigned* cbar = barr + (16 + jb) * 32;  // col-group j line

    // ---- stage both slices ONCE (128 KB) ----
    const int w = tid >> 6;
    const char* xsrc = (const char*)xs + (size_t)(ib * 512) * 128;
    const char* ysrc = (const char*)ys + (size_t)(jb * 512) * 128;
    #pragma unroll
    for (int r = 0; r < 4; r++) {
        GLD_LDS16(xsrc + r * 16384 + tid * 16, &mlds[r * 16384 + w * 1024]);
        GLD_LDS16(ysrc + r * 16384 + tid * 16, &mlds[65536 + r * 16384 + w * 1024]);
    }
    // (vmcnt drained by the syncthreads inside the first do_pass prologue)

    for (int t = 0; t < N_ITERS; t++) {
        const int par = t & 1;
        // f-pass: rows=X_i, cols=Y_j, bias from Pb written last g-pass
        do_pass(Pb[par ^ 1], lb2, Pf[par],
                512 * jb, jb * NR + 512 * ib, 0, 65536, mlds, cbl, comb);
        gsync_n(rbar, 16);                 // row-group i: Pf[par] slices ready
        // g-pass: rows=Y_j, cols=X_i, bias from Pf this iter
        do_pass(Pf[par], la2, Pb[par],
                512 * ib, ib * NR + 512 * jb, 65536, 0, mlds, cbl, comb);
        gsync_n(cbar, 16);                 // col-group j: Pb[par] slices ready
    }

    // finals (read Pb[1]/Pf[1]; write Pf[0]/Pb[0]; no barrier needed between)
    do_pass(Pb[1], lb2, Pff, 512 * jb, jb * NR + 512 * ib, 0, 65536,
            mlds, cbl, comb);
    do_pass(Pf[1], la2, Pgf, 512 * ib, ib * NR + 512 * jb, 65536, 0,
            mlds, cbl, comb);
    gsync_n(rbar, 16);                     // grid-equivalent sync:
    gsync_n(cbar, 16);                     // rows done, then columns-of-rows

    // ---- reduction stage 1: blocks 0..63, threads 0..255 ----
    if (bi < 64 && tid < 256) {
        int r = bi * 128 + (tid & 127);
        bool gsd = tid >= 128;                 // 0-127: f side, 128-255: g side
        float L  = merge16_l(gsd ? Pgf : Pff, r);
        float sq = gsd ? y2[r] : x2[r];
        float wv = gsd ? b[r]  : a[r];
        float v  = wv * (sq - EPSLN2 * L);
        v = wave_reduce_sum(v);
        if ((tid & 63) == 0) cbl[tid >> 6] = v;
    }
    __syncthreads();
    if (bi < 64 && tid == 0)
        red2[bi] = make_float2(cbl[0] + cbl[1], cbl[2] + cbl[3]);
    gsync_n(rbar, 16);                     // grid-equivalent sync
    gsync_n(cbar, 16);

    // ---- reduction stage 2: block 0, one wave ----
    if (bi == 0 && tid < 64) {
        float2 v = red2[tid];
        float da = wave_reduce_sum(v.x);
        float db = wave_reduce_sum(v.y);
        if (tid == 0) out[0] = da / sums[2] + db / sums[3];
    }
}

extern "C" void kernel_launch(void* const* d_in, const int* in_sizes, int n_in,
                              void* d_out, int out_size, void* d_ws, size_t ws_size,
                              hipStream_t stream) {
    const float* a = (const float*)d_in[0];
    const float* x = (const float*)d_in[1];
    const float* b = (const float*)d_in[2];
    const float* y = (const float*)d_in[3];

    char* ws = (char*)d_ws;
    short8* xs = (short8*)ws;                        // 1 MB stream layout
    short8* ys = (short8*)(ws + (1 << 20));          // 1 MB
    float* fp  = (float*)(ws + (2 << 20));
    float* x2  = fp;
    float* y2  = fp + NR;
    float* la2 = fp + 2 * NR;
    float* lb2 = fp + 3 * NR;
    float2* P   = (float2*)(fp + 4 * NR);            // 4 arrays x 1 MB
    float2* red2 = P + 4 * PSZ;                      // 64 entries
    float* sums  = (float*)(red2 + 64);              // 4 floats
    unsigned* barr = (unsigned*)(ws + (7 << 20));    // 32 lines x 128 B
    float* outp  = (float*)d_out;

    sums_kernel<<<1, 1024, 0, stream>>>(a, b, sums, barr);
    prep_kernel<<<(2 * NR * 8) / 256, 256, 0, stream>>>(x, y, a, b, sums,
                                                        xs, ys,
                                                        x2, y2, la2, lb2,
                                                        P + 3 * PSZ);  // Pb[1]

    void* args[] = { (void*)&xs, (void*)&ys, (void*)&la2, (void*)&lb2,
                     (void*)&P, (void*)&a, (void*)&b, (void*)&x2, (void*)&y2,
                     (void*)&red2, (void*)&sums, (void*)&barr, (void*)&outp };
    hipLaunchCooperativeKernel((void*)sink_kernel, dim3(256), dim3(1024),
                               args, 0, stream);
}

// Round 5
// 991.621 us; speedup vs baseline: 1.8809x; 1.5577x over previous
//
#include <hip/hip_runtime.h>
#include <hip/hip_bf16.h>

#define EPS       0.05f
#define N_ITERS   20
#define NR        8192      // N == M
#define DIM       64
#define LOG2E     1.4426950408889634f
#define LN2       0.6931471805599453f
#define S2        (2.0f * LOG2E / EPS)   // folded into xs at prep
#define EPSLN2    (EPS * LN2)
#define NEGINF    (-1e30f)
#define NSPLIT    16                     // column splits (partials per side)
#define SKIP_THR  125.0f                 // exp2 args below max-125 underflow

typedef __attribute__((ext_vector_type(8))) short short8;
typedef __attribute__((ext_vector_type(4))) float float4v;

#define GLD_LDS16(src, dst)                                              \
    __builtin_amdgcn_global_load_lds(                                    \
        (const __attribute__((address_space(1))) void*)(src),            \
        (__attribute__((address_space(3))) void*)(dst), 16, 0, 0)

__device__ __forceinline__ float wave_reduce_sum(float v) {
    #pragma unroll
    for (int m = 1; m < 64; m <<= 1) v += __shfl_xor(v, m, 64);
    return v;
}

// merged log2-LSE of NSPLIT partials for row/col i
__device__ __forceinline__ float merge16_l(const float2* __restrict__ P, int i) {
    float2 p[NSPLIT];
    float M = NEGINF;
    #pragma unroll
    for (int k = 0; k < NSPLIT; k++) {
        p[k] = P[k * NR + i];
        M = fmaxf(M, p[k].x);
    }
    float S = 0.f;
    #pragma unroll
    for (int k = 0; k < NSPLIT; k++)
        S += p[k].y * __builtin_amdgcn_exp2f(p[k].x - M);
    return M + __builtin_amdgcn_logf(S);   // log2 domain
}

// ---- setup: sums of a and b ------------------------------------------------
__global__ void sums_kernel(const float* __restrict__ a, const float* __restrict__ b,
                            float* __restrict__ sums) {
    __shared__ float red[32];
    int tid = threadIdx.x;
    float pa = 0.f, pb = 0.f;
    for (int i = tid; i < NR; i += blockDim.x) { pa += a[i]; pb += b[i]; }
    pa = wave_reduce_sum(pa);
    pb = wave_reduce_sum(pb);
    int wid = tid >> 6, ln = tid & 63;
    if (ln == 0) { red[wid] = pa; red[wid + 16] = pb; }
    __syncthreads();
    if (tid == 0) {
        float sa = 0.f, sb = 0.f;
        int nw = blockDim.x >> 6;
        for (int w = 0; w < nw; w++) { sa += red[w]; sb += red[w + 16]; }
        sums[0] = logf(sa); sums[1] = logf(sb); sums[2] = sa; sums[3] = sb;
    }
}

// ---- setup: bf16 stream-layout copies, norms, weights, initial partials ----
// xs pre-scaled by S2 so MFMA output is z directly (bias enters as C-operand).
__global__ void prep_kernel(const float* __restrict__ x, const float* __restrict__ y,
                            const float* __restrict__ a, const float* __restrict__ b,
                            const float* __restrict__ sums,
                            short8* __restrict__ xs, short8* __restrict__ ys,
                            float* __restrict__ x2, float* __restrict__ y2,
                            float* __restrict__ la2, float* __restrict__ lb2,
                            float2* __restrict__ Pb) {   // [NSPLIT][NR] g-partials
    int gid = blockIdx.x * 256 + threadIdx.x;
    bool isx = gid < NR * 8;
    int cid = isx ? gid : gid - NR * 8;
    int row = cid >> 3;
    int c   = cid & 7;
    const float4* src = (const float4*)(isx ? x : y);
    float4 v0 = src[row * 16 + c * 2];
    float4 v1 = src[row * 16 + c * 2 + 1];

    const float sc = isx ? S2 : 1.0f;
    short8 st;
    st[0] = __bfloat16_as_short(__float2bfloat16(v0.x * sc));
    st[1] = __bfloat16_as_short(__float2bfloat16(v0.y * sc));
    st[2] = __bfloat16_as_short(__float2bfloat16(v0.z * sc));
    st[3] = __bfloat16_as_short(__float2bfloat16(v0.w * sc));
    st[4] = __bfloat16_as_short(__float2bfloat16(v1.x * sc));
    st[5] = __bfloat16_as_short(__float2bfloat16(v1.y * sc));
    st[6] = __bfloat16_as_short(__float2bfloat16(v1.z * sc));
    st[7] = __bfloat16_as_short(__float2bfloat16(v1.w * sc));

    int T = row >> 4, ln = row & 15, f = c >> 2, q = c & 3;
    (isx ? xs : ys)[T * 128 + f * 64 + q * 16 + ln] = st;    // stream layout

    float sq = v0.x*v0.x + v0.y*v0.y + v0.z*v0.z + v0.w*v0.w
             + v1.x*v1.x + v1.y*v1.y + v1.z*v1.z + v1.w*v1.w;
    #pragma unroll
    for (int m = 1; m < 8; m <<= 1) sq += __shfl_xor(sq, m, 64);

    if (c == 0) {
        if (isx) {
            x2[row] = sq;
            la2[row] = (logf(a[row]) - sums[0]) * LOG2E;
        } else {
            y2[row] = sq;
            lb2[row] = (logf(b[row]) - sums[1]) * LOG2E;
            Pb[row] = make_float2(sq * (LOG2E / EPS), 1.0f);   // g = 0 initially
            #pragma unroll
            for (int k = 1; k < NSPLIT; k++)
                Pb[k * NR + row] = make_float2(NEGINF, 0.0f);
        }
    }
}

// ---- one softmin sweep (1/16 of the columns) -------------------------------
// R16 = R12 structure (multi-launch, proven) + two additions:
//  (1) underflow pruning: a 16x16 tile whose max z is > 125 below every
//      row's running max contributes only denormals (< 2^-125 each, summed
//      < 2^-112 vs ss >= 1) -> skip the 5 exp2 + LSE VALU. Bit-exact.
//  (2) XCD-chunked block remap: the 16 blocks sharing an X slice land on
//      one XCD -> xs/ys become L2-resident across passes (staging ~free).
__global__ __launch_bounds__(1024, 4) void pass_kernel(
        const short8* __restrict__ matXs,   // stream layout (rows)
        const short8* __restrict__ matYs,   // stream layout (cols)
        const float2* __restrict__ Pin,     // [NSPLIT][NR] column-side partials
        const float* __restrict__ lw2col,   // [NR]
        float2* __restrict__ Pout) {        // [NSPLIT][NR] row-side partials
    __shared__ __attribute__((aligned(16))) char xlds[65536];
    __shared__ __attribute__((aligned(16))) char ybuf[4][16384];
    __shared__ __attribute__((aligned(16))) float cbl[512];
    __shared__ float2 comb[512][5];         // [row][strip] (+1 pad)

    const int tid = threadIdx.x;
    const int bi  = blockIdx.x;
    const int v   = (bi & 7) * 32 + (bi >> 3);   // XCD-chunked remap
    const int q   = v & 15;                 // column split
    const int rg  = v >> 4;                 // row-group
    const int rb  = rg * 512;
    const int cb0 = q * 512;

    const int w    = tid >> 6;        // wave 0..15
    const int lane = tid & 63;
    const int quad = lane >> 4;
    const int ln   = lane & 15;
    const int cst  = w & 3;           // 32-col strip within chunk
    const int rq   = w >> 2;          // 128-row quarter

    // ---- issue ALL X staging + ALL FOUR Y chunks up front (async) ----
    const char* xsrc = (const char*)matXs + (size_t)rb * 128;   // 64 KB
    #pragma unroll
    for (int r = 0; r < 4; r++)
        GLD_LDS16(xsrc + r * 16384 + tid * 16, &xlds[r * 16384 + w * 1024]);
    const char* ysrc = (const char*)matYs + (size_t)cb0 * 128;  // 64 KB
    #pragma unroll
    for (int c = 0; c < 4; c++)
        GLD_LDS16(ysrc + c * 16384 + tid * 16, &ybuf[c][w * 1024]);
    __builtin_amdgcn_sched_barrier(0);

    // ---- prologue: merge 16 column partials -> cbl (threads 0..511) ----
    if (tid < 512) {
        int j = cb0 + tid;
        cbl[tid] = lw2col[j] - merge16_l(Pin, j);
    }
    __builtin_amdgcn_sched_barrier(0);
    // X + Y0 staged (Y1..Y3 may remain in flight); cbl ds_writes drained
    __builtin_amdgcn_s_waitcnt(0x0073);     // vmcnt(3) lgkmcnt(0)
    __builtin_amdgcn_s_barrier();
    __builtin_amdgcn_sched_barrier(0);

    // ---- X fragments from LDS: 8 row-tiles (rows rb + rq*128 + t*16 + ln) --
    short8 xf0[8], xf1[8];
    {
        const char* xw = &xlds[(rq * 8) * 2048];
        #pragma unroll
        for (int t = 0; t < 8; t++) {
            xf0[t] = *(const short8*)(xw + t * 2048 + lane * 16);
            xf1[t] = *(const short8*)(xw + t * 2048 + 1024 + lane * 16);
        }
    }

    float lm[8], ls[8];
    #pragma unroll
    for (int t = 0; t < 8; t++) { lm[t] = NEGINF; ls[t] = 0.f; }

    #pragma unroll
    for (int c = 0; c < 4; c++) {
        const char* base = &ybuf[c][0];
        #pragma unroll
        for (int uu = 0; uu < 2; uu++) {
            const int u = cst * 2 + uu;       // 16-col subtile within chunk
            short8 ya0 = *(const short8*)(base + u * 2048 + lane * 16);
            short8 ya1 = *(const short8*)(base + u * 2048 + 1024 + lane * 16);
            float4v cin = *(const float4v*)(cbl + (c * 8 + u) * 16 + quad * 4);

            #pragma unroll
            for (int tt = 0; tt < 8; tt++) {
                float4v acc = __builtin_amdgcn_mfma_f32_16x16x32_bf16(ya0, xf0[tt], cin, 0, 0, 0);
                acc = __builtin_amdgcn_mfma_f32_16x16x32_bf16(ya1, xf1[tt], acc, 0, 0, 0);
                float zm = fmaxf(fmaxf(acc[0], acc[1]), fmaxf(acc[2], acc[3]));
                // underflow-pruned online LSE (wave-uniform branch)
                if (__any(zm >= lm[tt] - SKIP_THR)) {
                    float mn = fmaxf(zm, lm[tt]);
                    float e  = __builtin_amdgcn_exp2f(lm[tt] - mn);
                    float p  = (__builtin_amdgcn_exp2f(acc[0] - mn)
                              + __builtin_amdgcn_exp2f(acc[1] - mn))
                             + (__builtin_amdgcn_exp2f(acc[2] - mn)
                              + __builtin_amdgcn_exp2f(acc[3] - mn));
                    ls[tt] = fmaf(ls[tt], e, p);
                    lm[tt] = mn;
                }
            }
        }
        if (c < 3) {
            __builtin_amdgcn_sched_barrier(0);
            if (c == 0)      __builtin_amdgcn_s_waitcnt(0x0072);  // vmcnt(2)
            else if (c == 1) __builtin_amdgcn_s_waitcnt(0x0071);  // vmcnt(1)
            else             __builtin_amdgcn_s_waitcnt(0x0070);  // vmcnt(0)
            __builtin_amdgcn_s_barrier();
            __builtin_amdgcn_sched_barrier(0);
        }
    }

    // combine across the 4 quads (same ln = same output rows)
    // (NEGINF,0) strips pass through exactly: exp2(-1e30 - M) flushes to 0.
    #pragma unroll
    for (int mask = 16; mask < 64; mask <<= 1) {
        #pragma unroll
        for (int t = 0; t < 8; t++) {
            float mo = __shfl_xor(lm[t], mask, 64);
            float so = __shfl_xor(ls[t], mask, 64);
            float M  = fmaxf(lm[t], mo);
            ls[t] = ls[t] * __builtin_amdgcn_exp2f(lm[t] - M)
                  + so    * __builtin_amdgcn_exp2f(mo    - M);
            lm[t] = M;
        }
    }

    __syncthreads();
    if (lane < 16) {
        #pragma unroll
        for (int t = 0; t < 8; t++)
            comb[rq * 128 + t * 16 + ln][cst] = make_float2(lm[t], ls[t]);
    }
    __syncthreads();

    // merge the 4 strips per row; write this split's partial
    if (tid < 512) {
        float2 cc0 = comb[tid][0];
        float M = cc0.x, S = cc0.y;
        #pragma unroll
        for (int cc = 1; cc < 4; cc++) {
            float2 p = comb[tid][cc];
            float Mn = fmaxf(M, p.x);
            S = S * __builtin_amdgcn_exp2f(M - Mn)
              + p.y * __builtin_amdgcn_exp2f(p.x - Mn);
            M = Mn;
        }
        Pout[q * NR + rb + tid] = make_float2(M, S);
    }
}

// ---- reduction stage 1: per-128-row partial dots (64 blocks) ---------------
__global__ void reduce1_kernel(const float* __restrict__ a, const float* __restrict__ b,
                               const float* __restrict__ x2, const float* __restrict__ y2,
                               const float2* __restrict__ Pff, const float2* __restrict__ Pgf,
                               float2* __restrict__ red2) {
    __shared__ float red[4];
    int tid = threadIdx.x;                    // 256 thr = 4 waves
    int r   = blockIdx.x * 128 + (tid & 127);
    bool gs = tid >= 128;                     // waves 0-1: f side, 2-3: g side
    float L  = merge16_l(gs ? Pgf : Pff, r);
    float sq = gs ? y2[r] : x2[r];
    float wv = gs ? b[r]  : a[r];
    float v  = wv * (sq - EPSLN2 * L);
    v = wave_reduce_sum(v);
    if ((tid & 63) == 0) red[tid >> 6] = v;
    __syncthreads();
    if (tid == 0) red2[blockIdx.x] = make_float2(red[0] + red[1], red[2] + red[3]);
}

// ---- reduction stage 2 -----------------------------------------------------
__global__ void reduce2_kernel(const float* __restrict__ sums,
                               const float2* __restrict__ red2,
                               float* __restrict__ out) {
    int tid = threadIdx.x;   // 64
    float2 v = red2[tid];
    float da = wave_reduce_sum(v.x);
    float db = wave_reduce_sum(v.y);
    if (tid == 0) out[0] = da / sums[2] + db / sums[3];
}

extern "C" void kernel_launch(void* const* d_in, const int* in_sizes, int n_in,
                              void* d_out, int out_size, void* d_ws, size_t ws_size,
                              hipStream_t stream) {
    const float* a = (const float*)d_in[0];
    const float* x = (const float*)d_in[1];
    const float* b = (const float*)d_in[2];
    const float* y = (const float*)d_in[3];

    char* ws = (char*)d_ws;
    short8* xs = (short8*)ws;                        // 1 MB stream layout
    short8* ys = (short8*)(ws + (1 << 20));          // 1 MB
    float* fp  = (float*)(ws + (2 << 20));
    float* x2  = fp;
    float* y2  = fp + NR;
    float* la2 = fp + 2 * NR;
    float* lb2 = fp + 3 * NR;
    float2* P   = (float2*)(fp + 4 * NR);
    float2* Pf  = P;                          // f-side partials [NSPLIT][NR]
    float2* Pb  = P + NSPLIT * NR;            // g-side partials
    float2* Pff = P + 2 * NSPLIT * NR;        // final f partials
    float2* Pgf = P + 3 * NSPLIT * NR;        // final g partials
    float2* red2 = P + 4 * NSPLIT * NR;       // 64 entries
    float* sums  = (float*)(red2 + 64);

    sums_kernel<<<1, 1024, 0, stream>>>(a, b, sums);
    prep_kernel<<<(2 * NR * 8) / 256, 256, 0, stream>>>(x, y, a, b, sums,
                                                        xs, ys,
                                                        x2, y2, la2, lb2, Pb);

    for (int it = 0; it < N_ITERS; it++) {
        // f-update: rows = x-side, cols = y-side biased by g-partials
        pass_kernel<<<256, 1024, 0, stream>>>(xs, ys, Pb, lb2, Pf);
        // g-update: rows = y-side, cols = x-side biased by f-partials
        pass_kernel<<<256, 1024, 0, stream>>>(ys, xs, Pf, la2, Pb);
    }
    // final symmetric update from detached potentials
    pass_kernel<<<256, 1024, 0, stream>>>(xs, ys, Pb, lb2, Pff);
    pass_kernel<<<256, 1024, 0, stream>>>(ys, xs, Pf, la2, Pgf);

    reduce1_kernel<<<64, 256, 0, stream>>>(a, b, x2, y2, Pff, Pgf, red2);
    reduce2_kernel<<<1, 64, 0, stream>>>(sums, red2, (float*)d_out);
}

// Round 6
// 885.415 us; speedup vs baseline: 2.1065x; 1.1200x over previous
//
#include <hip/hip_runtime.h>
#include <hip/hip_bf16.h>

#define EPS       0.05f
#define N_ITERS   20
#define NR        8192      // N == M
#define DIM       64
#define LOG2E     1.4426950408889634f
#define LN2       0.6931471805599453f
#define S2        (2.0f * LOG2E / EPS)   // folded into xs at prep
#define EPSLN2    (EPS * LN2)
#define NEGINF    (-1e30f)
#define NSPLIT    16                     // column splits (partials per side)

typedef __attribute__((ext_vector_type(8))) short short8;
typedef __attribute__((ext_vector_type(4))) float float4v;

#define GLD_LDS16(src, dst)                                              \
    __builtin_amdgcn_global_load_lds(                                    \
        (const __attribute__((address_space(1))) void*)(src),            \
        (__attribute__((address_space(3))) void*)(dst), 16, 0, 0)

__device__ __forceinline__ float wave_reduce_sum(float v) {
    #pragma unroll
    for (int m = 1; m < 64; m <<= 1) v += __shfl_xor(v, m, 64);
    return v;
}

// merged log2-LSE of NSPLIT partials for row/col i
__device__ __forceinline__ float merge16_l(const float2* __restrict__ P, int i) {
    float2 p[NSPLIT];
    float M = NEGINF;
    #pragma unroll
    for (int k = 0; k < NSPLIT; k++) {
        p[k] = P[k * NR + i];
        M = fmaxf(M, p[k].x);
    }
    float S = 0.f;
    #pragma unroll
    for (int k = 0; k < NSPLIT; k++)
        S += p[k].y * __builtin_amdgcn_exp2f(p[k].x - M);
    return M + __builtin_amdgcn_logf(S);   // log2 domain
}

// ---- setup: sums of a and b ------------------------------------------------
__global__ void sums_kernel(const float* __restrict__ a, const float* __restrict__ b,
                            float* __restrict__ sums) {
    __shared__ float red[32];
    int tid = threadIdx.x;
    float pa = 0.f, pb = 0.f;
    for (int i = tid; i < NR; i += blockDim.x) { pa += a[i]; pb += b[i]; }
    pa = wave_reduce_sum(pa);
    pb = wave_reduce_sum(pb);
    int wid = tid >> 6, ln = tid & 63;
    if (ln == 0) { red[wid] = pa; red[wid + 16] = pb; }
    __syncthreads();
    if (tid == 0) {
        float sa = 0.f, sb = 0.f;
        int nw = blockDim.x >> 6;
        for (int w = 0; w < nw; w++) { sa += red[w]; sb += red[w + 16]; }
        sums[0] = logf(sa); sums[1] = logf(sb); sums[2] = sa; sums[3] = sb;
    }
}

// ---- setup: bf16 stream-layout copies, norms, weights, initial partials ----
// xs pre-scaled by S2 so MFMA output is z directly (bias enters as C-operand).
__global__ void prep_kernel(const float* __restrict__ x, const float* __restrict__ y,
                            const float* __restrict__ a, const float* __restrict__ b,
                            const float* __restrict__ sums,
                            short8* __restrict__ xs, short8* __restrict__ ys,
                            float* __restrict__ x2, float* __restrict__ y2,
                            float* __restrict__ la2, float* __restrict__ lb2,
                            float2* __restrict__ Pb) {   // [NSPLIT][NR] g-partials
    int gid = blockIdx.x * 256 + threadIdx.x;
    bool isx = gid < NR * 8;
    int cid = isx ? gid : gid - NR * 8;
    int row = cid >> 3;
    int c   = cid & 7;
    const float4* src = (const float4*)(isx ? x : y);
    float4 v0 = src[row * 16 + c * 2];
    float4 v1 = src[row * 16 + c * 2 + 1];

    const float sc = isx ? S2 : 1.0f;
    short8 st;
    st[0] = __bfloat16_as_short(__float2bfloat16(v0.x * sc));
    st[1] = __bfloat16_as_short(__float2bfloat16(v0.y * sc));
    st[2] = __bfloat16_as_short(__float2bfloat16(v0.z * sc));
    st[3] = __bfloat16_as_short(__float2bfloat16(v0.w * sc));
    st[4] = __bfloat16_as_short(__float2bfloat16(v1.x * sc));
    st[5] = __bfloat16_as_short(__float2bfloat16(v1.y * sc));
    st[6] = __bfloat16_as_short(__float2bfloat16(v1.z * sc));
    st[7] = __bfloat16_as_short(__float2bfloat16(v1.w * sc));

    int T = row >> 4, ln = row & 15, f = c >> 2, q = c & 3;
    (isx ? xs : ys)[T * 128 + f * 64 + q * 16 + ln] = st;    // stream layout

    float sq = v0.x*v0.x + v0.y*v0.y + v0.z*v0.z + v0.w*v0.w
             + v1.x*v1.x + v1.y*v1.y + v1.z*v1.z + v1.w*v1.w;
    #pragma unroll
    for (int m = 1; m < 8; m <<= 1) sq += __shfl_xor(sq, m, 64);

    if (c == 0) {
        if (isx) {
            x2[row] = sq;
            la2[row] = (logf(a[row]) - sums[0]) * LOG2E;
        } else {
            y2[row] = sq;
            lb2[row] = (logf(b[row]) - sums[1]) * LOG2E;
            Pb[row] = make_float2(sq * (LOG2E / EPS), 1.0f);   // g = 0 initially
            #pragma unroll
            for (int k = 1; k < NSPLIT; k++)
                Pb[k * NR + row] = make_float2(NEGINF, 0.0f);
        }
    }
}

// acc already IS z (bias folded into MFMA C-operand, S2 folded into data).
#define LSE4(acc, mm, ss)                                                \
    {                                                                    \
        float z0 = (acc)[0], z1 = (acc)[1];                              \
        float z2 = (acc)[2], z3 = (acc)[3];                              \
        float mn = fmaxf(fmaxf(fmaxf(z0, z1), fmaxf(z2, z3)), (mm));     \
        float e  = __builtin_amdgcn_exp2f((mm) - mn);                    \
        float p  = (__builtin_amdgcn_exp2f(z0 - mn)                      \
                  + __builtin_amdgcn_exp2f(z1 - mn))                     \
                 + (__builtin_amdgcn_exp2f(z2 - mn)                      \
                  + __builtin_amdgcn_exp2f(z3 - mn));                    \
        (ss) = fmaf((ss), e, p);                                         \
        (mm) = mn;                                                       \
    }

// ---- one softmin sweep (1/16 of the columns) -------------------------------
// R17: 256x512 tile, 512 threads, grid 512 => 2 blocks/CU (LDS 72 KB).
// Staging latency, prologue, and barriers hide behind the sibling block.
// X fragments load global->register directly (stream layout is contiguous
// per fragment); all of Y (64 KB) stays LDS-resident: no mid-loop barriers.
__global__ __launch_bounds__(512, 4) void pass_kernel(
        const short8* __restrict__ matXs,   // stream layout (rows)
        const short8* __restrict__ matYs,   // stream layout (cols)
        const float2* __restrict__ Pin,     // [NSPLIT][NR] column-side partials
        const float* __restrict__ lw2col,   // [NR]
        float2* __restrict__ Pout) {        // [NSPLIT][NR] row-side partials
    __shared__ __attribute__((aligned(16))) char ylds[65536];
    __shared__ __attribute__((aligned(16))) float cbl[512];
    __shared__ float2 comb[256][3];         // [row][strip] (+1 pad)

    const int tid = threadIdx.x;
    const int bi  = blockIdx.x;
    const int q   = bi & 15;                // column split
    const int rg  = bi >> 4;                // row-group 0..31
    const int rb  = rg * 256;
    const int cb0 = q * 512;

    const int w    = tid >> 6;        // wave 0..7
    const int lane = tid & 63;
    const int quad = lane >> 4;
    const int ln   = lane & 15;
    const int cst  = w & 1;           // 256-col half
    const int rq   = w >> 1;          // 64-row quarter (4 row-tiles)

    // ---- Y staging: 64 KB via 8 async global->LDS calls ----
    const char* ysrc = (const char*)matYs + (size_t)cb0 * 128;
    #pragma unroll
    for (int k = 0; k < 8; k++)
        GLD_LDS16(ysrc + k * 8192 + tid * 16, &ylds[k * 8192 + w * 1024]);

    // ---- X fragments: global -> registers (rows rb + rq*64 + t*16 + ln) ----
    const char* xsrc = (const char*)matXs + (size_t)rb * 128
                     + (size_t)(rq * 4) * 2048 + (size_t)lane * 16;
    short8 xf0[4], xf1[4];
    #pragma unroll
    for (int t = 0; t < 4; t++) {
        xf0[t] = *(const short8*)(xsrc + t * 2048);
        xf1[t] = *(const short8*)(xsrc + t * 2048 + 1024);
    }

    // ---- prologue: merge 16 column partials -> cbl (1 col/thread) ----
    {
        int j = cb0 + tid;
        cbl[tid] = lw2col[j] - merge16_l(Pin, j);
    }
    __syncthreads();   // full drain: Y staged, cbl ready (X regs via data dep)

    float lm[4], ls[4];
    #pragma unroll
    for (int t = 0; t < 4; t++) { lm[t] = NEGINF; ls[t] = 0.f; }

    const char* cw  = &ylds[cst * 32768];
    const float* cbw = cbl + cst * 256;
    #pragma unroll 4
    for (int u = 0; u < 16; u++) {
        short8 ya0 = *(const short8*)(cw + u * 2048 + lane * 16);
        short8 ya1 = *(const short8*)(cw + u * 2048 + 1024 + lane * 16);
        float4v cin = *(const float4v*)(cbw + u * 16 + quad * 4);
        #pragma unroll
        for (int tt = 0; tt < 4; tt++) {
            float4v acc = __builtin_amdgcn_mfma_f32_16x16x32_bf16(ya0, xf0[tt], cin, 0, 0, 0);
            acc = __builtin_amdgcn_mfma_f32_16x16x32_bf16(ya1, xf1[tt], acc, 0, 0, 0);
            LSE4(acc, lm[tt], ls[tt]);
        }
    }

    // combine across the 4 quads (same ln = same output rows)
    #pragma unroll
    for (int mask = 16; mask < 64; mask <<= 1) {
        #pragma unroll
        for (int t = 0; t < 4; t++) {
            float mo = __shfl_xor(lm[t], mask, 64);
            float so = __shfl_xor(ls[t], mask, 64);
            float M  = fmaxf(lm[t], mo);
            ls[t] = ls[t] * __builtin_amdgcn_exp2f(lm[t] - M)
                  + so    * __builtin_amdgcn_exp2f(mo    - M);
            lm[t] = M;
        }
    }

    if (lane < 16) {
        #pragma unroll
        for (int t = 0; t < 4; t++)
            comb[rq * 64 + t * 16 + ln][cst] = make_float2(lm[t], ls[t]);
    }
    __syncthreads();

    // merge the 2 strips per row; write this split's partial
    if (tid < 256) {
        float2 c0 = comb[tid][0], c1 = comb[tid][1];
        float M = fmaxf(c0.x, c1.x);
        float S = c0.y * __builtin_amdgcn_exp2f(c0.x - M)
                + c1.y * __builtin_amdgcn_exp2f(c1.x - M);
        Pout[q * NR + rb + tid] = make_float2(M, S);
    }
}

// ---- reduction stage 1: per-128-row partial dots (64 blocks) ---------------
__global__ void reduce1_kernel(const float* __restrict__ a, const float* __restrict__ b,
                               const float* __restrict__ x2, const float* __restrict__ y2,
                               const float2* __restrict__ Pff, const float2* __restrict__ Pgf,
                               float2* __restrict__ red2) {
    __shared__ float red[4];
    int tid = threadIdx.x;                    // 256 thr = 4 waves
    int r   = blockIdx.x * 128 + (tid & 127);
    bool gs = tid >= 128;                     // waves 0-1: f side, 2-3: g side
    float L  = merge16_l(gs ? Pgf : Pff, r);
    float sq = gs ? y2[r] : x2[r];
    float wv = gs ? b[r]  : a[r];
    float v  = wv * (sq - EPSLN2 * L);
    v = wave_reduce_sum(v);
    if ((tid & 63) == 0) red[tid >> 6] = v;
    __syncthreads();
    if (tid == 0) red2[blockIdx.x] = make_float2(red[0] + red[1], red[2] + red[3]);
}

// ---- reduction stage 2 -----------------------------------------------------
__global__ void reduce2_kernel(const float* __restrict__ sums,
                               const float2* __restrict__ red2,
                               float* __restrict__ out) {
    int tid = threadIdx.x;   // 64
    float2 v = red2[tid];
    float da = wave_reduce_sum(v.x);
    float db = wave_reduce_sum(v.y);
    if (tid == 0) out[0] = da / sums[2] + db / sums[3];
}

extern "C" void kernel_launch(void* const* d_in, const int* in_sizes, int n_in,
                              void* d_out, int out_size, void* d_ws, size_t ws_size,
                              hipStream_t stream) {
    const float* a = (const float*)d_in[0];
    const float* x = (const float*)d_in[1];
    const float* b = (const float*)d_in[2];
    const float* y = (const float*)d_in[3];

    char* ws = (char*)d_ws;
    short8* xs = (short8*)ws;                        // 1 MB stream layout
    short8* ys = (short8*)(ws + (1 << 20));          // 1 MB
    float* fp  = (float*)(ws + (2 << 20));
    float* x2  = fp;
    float* y2  = fp + NR;
    float* la2 = fp + 2 * NR;
    float* lb2 = fp + 3 * NR;
    float2* P   = (float2*)(fp + 4 * NR);
    float2* Pf  = P;                          // f-side partials [NSPLIT][NR]
    float2* Pb  = P + NSPLIT * NR;            // g-side partials
    float2* Pff = P + 2 * NSPLIT * NR;        // final f partials
    float2* Pgf = P + 3 * NSPLIT * NR;        // final g partials
    float2* red2 = P + 4 * NSPLIT * NR;       // 64 entries
    float* sums  = (float*)(red2 + 64);

    sums_kernel<<<1, 1024, 0, stream>>>(a, b, sums);
    prep_kernel<<<(2 * NR * 8) / 256, 256, 0, stream>>>(x, y, a, b, sums,
                                                        xs, ys,
                                                        x2, y2, la2, lb2, Pb);

    for (int it = 0; it < N_ITERS; it++) {
        // f-update: rows = x-side, cols = y-side biased by g-partials
        pass_kernel<<<512, 512, 0, stream>>>(xs, ys, Pb, lb2, Pf);
        // g-update: rows = y-side, cols = x-side biased by f-partials
        pass_kernel<<<512, 512, 0, stream>>>(ys, xs, Pf, la2, Pb);
    }
    // final symmetric update from detached potentials
    pass_kernel<<<512, 512, 0, stream>>>(xs, ys, Pb, lb2, Pff);
    pass_kernel<<<512, 512, 0, stream>>>(ys, xs, Pf, la2, Pgf);

    reduce1_kernel<<<64, 256, 0, stream>>>(a, b, x2, y2, Pff, Pgf, red2);
    reduce2_kernel<<<1, 64, 0, stream>>>(sums, red2, (float*)d_out);
}

// Round 7
// 872.517 us; speedup vs baseline: 2.1376x; 1.0148x over previous
//
#include <hip/hip_runtime.h>
#include <hip/hip_bf16.h>

#define EPS       0.05f
#define N_ITERS   20
#define NR        8192      // N == M
#define DIM       64
#define LOG2E     1.4426950408889634f
#define LN2       0.6931471805599453f
#define S2        (2.0f * LOG2E / EPS)   // folded into xs at prep
#define EPSLN2    (EPS * LN2)
#define NEGINF    (-1e30f)
#define NSPLIT    16                     // column splits (partials per side)
#define PSZ       (NSPLIT * NR)          // one partial array (8B elems)

typedef __attribute__((ext_vector_type(8))) short short8;
typedef __attribute__((ext_vector_type(4))) float float4v;
typedef unsigned long long u64;

#define GLD_LDS16(src, dst)                                              \
    __builtin_amdgcn_global_load_lds(                                    \
        (const __attribute__((address_space(1))) void*)(src),            \
        (__attribute__((address_space(3))) void*)(dst), 16, 0, 0)

// ---- L3-coherent (agent-scope, L2-bypassing) float2 transport --------------
__device__ __forceinline__ float2 ld_f2a(const u64* p) {
    u64 v = __hip_atomic_load(p, __ATOMIC_RELAXED, __HIP_MEMORY_SCOPE_AGENT);
    union { u64 u; float2 f; } c; c.u = v; return c.f;
}
__device__ __forceinline__ void st_f2a(u64* p, float2 f) {
    union { u64 u; float2 f2; } c; c.f2 = f;
    __hip_atomic_store(p, c.u, __ATOMIC_RELAXED, __HIP_MEMORY_SCOPE_AGENT);
}

__device__ __forceinline__ float wave_reduce_sum(float v) {
    #pragma unroll
    for (int m = 1; m < 64; m <<= 1) v += __shfl_xor(v, m, 64);
    return v;
}

// merged log2-LSE of NSPLIT partials for row/col i (L3-coherent reads)
__device__ __forceinline__ float merge16_a(const u64* P, int i) {
    float2 p[NSPLIT];
    float M = NEGINF;
    #pragma unroll
    for (int k = 0; k < NSPLIT; k++) {
        p[k] = ld_f2a(P + k * NR + i);
        M = fmaxf(M, p[k].x);
    }
    float S = 0.f;
    #pragma unroll
    for (int k = 0; k < NSPLIT; k++)
        S += p[k].y * __builtin_amdgcn_exp2f(p[k].x - M);
    return M + __builtin_amdgcn_logf(S);   // log2 domain
}

// ---- n-block barrier, FENCE-FREE -------------------------------------------
// R15's proven counter+generation protocol minus the __threadfence pair.
// Ordering: __syncthreads drains all waves' vmcnt (stores ACKed at L3,
// since data moves via L2-bypassing atomics) before the arrival RMW.
__device__ __forceinline__ void gsync_n(unsigned* bar, unsigned n) {
    __syncthreads();
    if (threadIdx.x == 0) {
        unsigned g = __hip_atomic_load(&bar[1], __ATOMIC_RELAXED,
                                       __HIP_MEMORY_SCOPE_AGENT);
        unsigned a = __hip_atomic_fetch_add(&bar[0], 1u, __ATOMIC_RELAXED,
                                            __HIP_MEMORY_SCOPE_AGENT);
        if (a == n - 1u) {                                 // last arriver
            __hip_atomic_store(&bar[0], 0u, __ATOMIC_RELAXED,
                               __HIP_MEMORY_SCOPE_AGENT);
            __hip_atomic_store(&bar[1], g + 1u, __ATOMIC_RELAXED,
                               __HIP_MEMORY_SCOPE_AGENT);
        } else {
            while (__hip_atomic_load(&bar[1], __ATOMIC_RELAXED,
                                     __HIP_MEMORY_SCOPE_AGENT) == g)
                __builtin_amdgcn_s_sleep(1);
        }
    }
    __syncthreads();
}

// ---- setup: sums of a and b + zero all barrier lines -----------------------
__global__ void sums_kernel(const float* __restrict__ a, const float* __restrict__ b,
                            float* __restrict__ sums, unsigned* __restrict__ barr) {
    __shared__ float red[32];
    int tid = threadIdx.x;
    if (tid < 1024) barr[tid] = 0u;        // 32 groups x 32 u32 lines
    float pa = 0.f, pb = 0.f;
    for (int i = tid; i < NR; i += blockDim.x) { pa += a[i]; pb += b[i]; }
    pa = wave_reduce_sum(pa);
    pb = wave_reduce_sum(pb);
    int wid = tid >> 6, ln = tid & 63;
    if (ln == 0) { red[wid] = pa; red[wid + 16] = pb; }
    __syncthreads();
    if (tid == 0) {
        float sa = 0.f, sb = 0.f;
        int nw = blockDim.x >> 6;
        for (int w = 0; w < nw; w++) { sa += red[w]; sb += red[w + 16]; }
        sums[0] = logf(sa); sums[1] = logf(sb); sums[2] = sa; sums[3] = sb;
    }
}

// ---- setup: bf16 stream-layout copies, norms, weights, initial partials ----
// xs pre-scaled by S2 so MFMA output is z directly (bias enters as C-operand).
__global__ void prep_kernel(const float* __restrict__ x, const float* __restrict__ y,
                            const float* __restrict__ a, const float* __restrict__ b,
                            const float* __restrict__ sums,
                            short8* __restrict__ xs, short8* __restrict__ ys,
                            float* __restrict__ x2, float* __restrict__ y2,
                            float* __restrict__ la2, float* __restrict__ lb2,
                            float2* __restrict__ Pb1) {  // initial g-partials
    int gid = blockIdx.x * 256 + threadIdx.x;
    bool isx = gid < NR * 8;
    int cid = isx ? gid : gid - NR * 8;
    int row = cid >> 3;
    int c   = cid & 7;
    const float4* src = (const float4*)(isx ? x : y);
    float4 v0 = src[row * 16 + c * 2];
    float4 v1 = src[row * 16 + c * 2 + 1];

    const float sc = isx ? S2 : 1.0f;
    short8 st;
    st[0] = __bfloat16_as_short(__float2bfloat16(v0.x * sc));
    st[1] = __bfloat16_as_short(__float2bfloat16(v0.y * sc));
    st[2] = __bfloat16_as_short(__float2bfloat16(v0.z * sc));
    st[3] = __bfloat16_as_short(__float2bfloat16(v0.w * sc));
    st[4] = __bfloat16_as_short(__float2bfloat16(v1.x * sc));
    st[5] = __bfloat16_as_short(__float2bfloat16(v1.y * sc));
    st[6] = __bfloat16_as_short(__float2bfloat16(v1.z * sc));
    st[7] = __bfloat16_as_short(__float2bfloat16(v1.w * sc));

    int T = row >> 4, ln = row & 15, f = c >> 2, q = c & 3;
    (isx ? xs : ys)[T * 128 + f * 64 + q * 16 + ln] = st;    // stream layout

    float sq = v0.x*v0.x + v0.y*v0.y + v0.z*v0.z + v0.w*v0.w
             + v1.x*v1.x + v1.y*v1.y + v1.z*v1.z + v1.w*v1.w;
    #pragma unroll
    for (int m = 1; m < 8; m <<= 1) sq += __shfl_xor(sq, m, 64);

    if (c == 0) {
        if (isx) {
            x2[row] = sq;
            la2[row] = (logf(a[row]) - sums[0]) * LOG2E;
        } else {
            y2[row] = sq;
            lb2[row] = (logf(b[row]) - sums[1]) * LOG2E;
            Pb1[row] = make_float2(sq * (LOG2E / EPS), 1.0f);  // g = 0 initially
            #pragma unroll
            for (int k = 1; k < NSPLIT; k++)
                Pb1[k * NR + row] = make_float2(NEGINF, 0.0f);
        }
    }
}

// acc already IS z (bias folded into MFMA C-operand, S2 folded into data).
#define LSE4(acc, mm, ss)                                                \
    {                                                                    \
        float z0 = (acc)[0], z1 = (acc)[1];                              \
        float z2 = (acc)[2], z3 = (acc)[3];                              \
        float mn = fmaxf(fmaxf(fmaxf(z0, z1), fmaxf(z2, z3)), (mm));     \
        float e  = __builtin_amdgcn_exp2f((mm) - mn);                    \
        float p  = (__builtin_amdgcn_exp2f(z0 - mn)                      \
                  + __builtin_amdgcn_exp2f(z1 - mn))                     \
                 + (__builtin_amdgcn_exp2f(z2 - mn)                      \
                  + __builtin_amdgcn_exp2f(z3 - mn));                    \
        (ss) = fmaf((ss), e, p);                                         \
        (mm) = mn;                                                       \
    }

// ---- one softmin pass over the block's resident 512x512 tile ---------------
__device__ __forceinline__ void do_pass(
        const u64* Pin, const float* lw, u64* Pout,
        int colbase, int outidx, int roff, int coff,
        char* mlds, float* cbl, float2 (*comb)[3]) {
    const int tid = threadIdx.x;
    const int w   = tid >> 6, lane = tid & 63;
    const int quad = lane >> 4, ln = lane & 15;
    const int cst = w & 1, rq = w >> 1;

    // prologue: merge 16 column partials -> cbl (L3-coherent reads)
    if (tid < 512) {
        int jj = colbase + tid;
        cbl[tid] = lw[jj] - merge16_a(Pin, jj);
    }
    __syncthreads();

    // row fragments from LDS: 4 tiles (rows rq*64 + t*16 + ln)
    short8 rf0[4], rf1[4];
    {
        const char* rw = &mlds[roff + rq * 8192];
        #pragma unroll
        for (int t = 0; t < 4; t++) {
            rf0[t] = *(const short8*)(rw + t * 2048 + lane * 16);
            rf1[t] = *(const short8*)(rw + t * 2048 + 1024 + lane * 16);
        }
    }

    float lm[4], ls[4];
    #pragma unroll
    for (int t = 0; t < 4; t++) { lm[t] = NEGINF; ls[t] = 0.f; }

    const char* cw = &mlds[coff + cst * 32768];
    const float* cbw = cbl + cst * 256;
    #pragma unroll 4
    for (int u = 0; u < 16; u++) {
        short8 ya0 = *(const short8*)(cw + u * 2048 + lane * 16);
        short8 ya1 = *(const short8*)(cw + u * 2048 + 1024 + lane * 16);
        float4v cin = *(const float4v*)(cbw + u * 16 + quad * 4);
        #pragma unroll
        for (int tt = 0; tt < 4; tt++) {
            float4v acc = __builtin_amdgcn_mfma_f32_16x16x32_bf16(ya0, rf0[tt], cin, 0, 0, 0);
            acc = __builtin_amdgcn_mfma_f32_16x16x32_bf16(ya1, rf1[tt], acc, 0, 0, 0);
            LSE4(acc, lm[tt], ls[tt]);
        }
    }

    // combine across the 4 quads (same ln = same output rows)
    #pragma unroll
    for (int mask = 16; mask < 64; mask <<= 1) {
        #pragma unroll
        for (int t = 0; t < 4; t++) {
            float mo = __shfl_xor(lm[t], mask, 64);
            float so = __shfl_xor(ls[t], mask, 64);
            float M  = fmaxf(lm[t], mo);
            ls[t] = ls[t] * __builtin_amdgcn_exp2f(lm[t] - M)
                  + so    * __builtin_amdgcn_exp2f(mo    - M);
            lm[t] = M;
        }
    }

    __syncthreads();   // comb reuse safe across passes
    if (lane < 16) {
        #pragma unroll
        for (int t = 0; t < 4; t++)
            comb[rq * 64 + t * 16 + ln][cst] = make_float2(lm[t], ls[t]);
    }
    __syncthreads();

    // merge the 2 strips per row; write this split's partial (L3-coherent)
    if (tid < 512) {
        float2 c0 = comb[tid][0], c1 = comb[tid][1];
        float M = fmaxf(c0.x, c1.x);
        float S = c0.y * __builtin_amdgcn_exp2f(c0.x - M)
                + c1.y * __builtin_amdgcn_exp2f(c1.x - M);
        st_f2a(Pout + outidx + tid, make_float2(M, S));
    }
}

// ---- persistent cooperative kernel: all 42 passes + reduction --------------
// Block (i,j) holds X-slice i and Y-slice j in LDS, staged ONCE.
// All cross-block data (P arrays, red2) moves via L2-bypassing agent atomics;
// barriers are fence-free -> per-XCD L2 never invalidated, xs/ys/lw stay warm.
__global__ __launch_bounds__(1024, 4) void sink_kernel(
        const short8* __restrict__ xs, const short8* __restrict__ ys,
        const float* __restrict__ la2, const float* __restrict__ lb2,
        u64* P,                          // Pf0|Pf1|Pb0|Pb1 (no restrict)
        const float* __restrict__ a, const float* __restrict__ b,
        const float* __restrict__ x2, const float* __restrict__ y2,
        u64* red2, const float* __restrict__ sums,
        unsigned* barr, float* out) {
    __shared__ __attribute__((aligned(16))) char mlds[131072];  // X | Y
    __shared__ __attribute__((aligned(16))) float cbl[512];
    __shared__ float2 comb[512][3];      // [row][strip] (+1 pad)

    const int tid = threadIdx.x;
    const int bi  = blockIdx.x;
    const int ib  = bi >> 4, jb = bi & 15;

    u64* Pf[2] = { P,           P + PSZ };
    u64* Pb[2] = { P + 2 * PSZ, P + 3 * PSZ };
    u64* Pff   = P;                      // alias Pf[0] (dead after iter 19)
    u64* Pgf   = P + 2 * PSZ;            // alias Pb[0]
    unsigned* rbar = barr + ib * 32;         // row-group i line
    unsigned* cbar = barr + (16 + jb) * 32;  // col-group j line

    // ---- stage both slices ONCE (128 KB) ----
    const int w = tid >> 6;
    const char* xsrc = (const char*)xs + (size_t)(ib * 512) * 128;
    const char* ysrc = (const char*)ys + (size_t)(jb * 512) * 128;
    #pragma unroll
    for (int r = 0; r < 4; r++) {
        GLD_LDS16(xsrc + r * 16384 + tid * 16, &mlds[r * 16384 + w * 1024]);
        GLD_LDS16(ysrc + r * 16384 + tid * 16, &mlds[65536 + r * 16384 + w * 1024]);
    }
    // (vmcnt drained by the syncthreads inside the first do_pass prologue)

    for (int t = 0; t < N_ITERS; t++) {
        const int par = t & 1;
        // f-pass: rows=X_i, cols=Y_j, bias from Pb written last g-pass
        do_pass(Pb[par ^ 1], lb2, Pf[par],
                512 * jb, jb * NR + 512 * ib, 0, 65536, mlds, cbl, comb);
        gsync_n(rbar, 16);                 // row-group i: Pf[par] slices ready
        // g-pass: rows=Y_j, cols=X_i, bias from Pf this iter
        do_pass(Pf[par], la2, Pb[par],
                512 * ib, ib * NR + 512 * jb, 65536, 0, mlds, cbl, comb);
        gsync_n(cbar, 16);                 // col-group j: Pb[par] slices ready
    }

    // finals (read Pb[1]/Pf[1]; write Pf[0]/Pb[0]; independent of each other)
    do_pass(Pb[1], lb2, Pff, 512 * jb, jb * NR + 512 * ib, 0, 65536,
            mlds, cbl, comb);
    do_pass(Pf[1], la2, Pgf, 512 * ib, ib * NR + 512 * jb, 65536, 0,
            mlds, cbl, comb);
    gsync_n(rbar, 16);                     // grid-equivalent sync:
    gsync_n(cbar, 16);                     // rows done, then columns-of-rows

    // ---- reduction stage 1: blocks 0..63, threads 0..255 ----
    if (bi < 64 && tid < 256) {
        int r = bi * 128 + (tid & 127);
        bool gsd = tid >= 128;                 // 0-127: f side, 128-255: g side
        float L  = merge16_a(gsd ? Pgf : Pff, r);
        float sq = gsd ? y2[r] : x2[r];
        float wv = gsd ? b[r]  : a[r];
        float v  = wv * (sq - EPSLN2 * L);
        v = wave_reduce_sum(v);
        if ((tid & 63) == 0) cbl[tid >> 6] = v;
    }
    __syncthreads();
    if (bi < 64 && tid == 0)
        st_f2a(red2 + bi, make_float2(cbl[0] + cbl[1], cbl[2] + cbl[3]));
    gsync_n(rbar, 16);                     // grid-equivalent sync
    gsync_n(cbar, 16);

    // ---- reduction stage 2: block 0, one wave ----
    if (bi == 0 && tid < 64) {
        float2 v = ld_f2a(red2 + tid);
        float da = wave_reduce_sum(v.x);
        float db = wave_reduce_sum(v.y);
        if (tid == 0) out[0] = da / sums[2] + db / sums[3];
    }
}

extern "C" void kernel_launch(void* const* d_in, const int* in_sizes, int n_in,
                              void* d_out, int out_size, void* d_ws, size_t ws_size,
                              hipStream_t stream) {
    const float* a = (const float*)d_in[0];
    const float* x = (const float*)d_in[1];
    const float* b = (const float*)d_in[2];
    const float* y = (const float*)d_in[3];

    char* ws = (char*)d_ws;
    short8* xs = (short8*)ws;                        // 1 MB stream layout
    short8* ys = (short8*)(ws + (1 << 20));          // 1 MB
    float* fp  = (float*)(ws + (2 << 20));
    float* x2  = fp;
    float* y2  = fp + NR;
    float* la2 = fp + 2 * NR;
    float* lb2 = fp + 3 * NR;
    u64* P     = (u64*)(fp + 4 * NR);                // 4 arrays x 1 MB
    u64* red2  = P + 4 * PSZ;                        // 64 entries
    float* sums  = (float*)(red2 + 64);              // 4 floats
    unsigned* barr = (unsigned*)(ws + (7 << 20));    // 32 lines x 128 B
    float* outp  = (float*)d_out;

    sums_kernel<<<1, 1024, 0, stream>>>(a, b, sums, barr);
    prep_kernel<<<(2 * NR * 8) / 256, 256, 0, stream>>>(x, y, a, b, sums,
                                                        xs, ys,
                                                        x2, y2, la2, lb2,
                                                        (float2*)(P + 3 * PSZ));

    void* args[] = { (void*)&xs, (void*)&ys, (void*)&la2, (void*)&lb2,
                     (void*)&P, (void*)&a, (void*)&b, (void*)&x2, (void*)&y2,
                     (void*)&red2, (void*)&sums, (void*)&barr, (void*)&outp };
    hipLaunchCooperativeKernel((void*)sink_kernel, dim3(256), dim3(1024),
                               args, 0, stream);
}

// Round 9
// 871.819 us; speedup vs baseline: 2.1393x; 1.0008x over previous
//
#include <hip/hip_runtime.h>
#include <hip/hip_bf16.h>

#define EPS       0.05f
#define N_ITERS   20
#define NR        8192      // N == M
#define DIM       64
#define LOG2E     1.4426950408889634f
#define LN2       0.6931471805599453f
#define S2        (2.0f * LOG2E / EPS)   // folded into xs at prep
#define EPSLN2    (EPS * LN2)
#define NEGINF    (-1e30f)
#define NSPLIT    16                     // column splits (partials per side)
#define PSZ       (NSPLIT * NR)          // one partial array (8B elems)

typedef __attribute__((ext_vector_type(8))) short short8;
typedef __attribute__((ext_vector_type(4))) float float4v;
typedef unsigned long long u64;

#define GLD_LDS16(src, dst)                                              \
    __builtin_amdgcn_global_load_lds(                                    \
        (const __attribute__((address_space(1))) void*)(src),            \
        (__attribute__((address_space(3))) void*)(dst), 16, 0, 0)

// ---- L3-coherent (agent-scope, L2-bypassing) float2 transport --------------
__device__ __forceinline__ float2 ld_f2a(const u64* p) {
    u64 v = __hip_atomic_load(p, __ATOMIC_RELAXED, __HIP_MEMORY_SCOPE_AGENT);
    union { u64 u; float2 f; } c; c.u = v; return c.f;
}
__device__ __forceinline__ void st_f2a(u64* p, float2 f) {
    union { u64 u; float2 f2; } c; c.f2 = f;
    __hip_atomic_store(p, c.u, __ATOMIC_RELAXED, __HIP_MEMORY_SCOPE_AGENT);
}

__device__ __forceinline__ float wave_reduce_sum(float v) {
    #pragma unroll
    for (int m = 1; m < 64; m <<= 1) v += __shfl_xor(v, m, 64);
    return v;
}

// merged log2-LSE of NSPLIT partials for row/col i (L3-coherent reads)
__device__ __forceinline__ float merge16_a(const u64* P, int i) {
    float2 p[NSPLIT];
    float M = NEGINF;
    #pragma unroll
    for (int k = 0; k < NSPLIT; k++) {
        p[k] = ld_f2a(P + k * NR + i);
        M = fmaxf(M, p[k].x);
    }
    float S = 0.f;
    #pragma unroll
    for (int k = 0; k < NSPLIT; k++)
        S += p[k].y * __builtin_amdgcn_exp2f(p[k].x - M);
    return M + __builtin_amdgcn_logf(S);   // log2 domain
}

// ---- n-block fence-free barrier (R18-proven on HW) -------------------------
__device__ __forceinline__ void gsync_n(unsigned* bar, unsigned n) {
    __syncthreads();
    if (threadIdx.x == 0) {
        unsigned g = __hip_atomic_load(&bar[1], __ATOMIC_RELAXED,
                                       __HIP_MEMORY_SCOPE_AGENT);
        unsigned a = __hip_atomic_fetch_add(&bar[0], 1u, __ATOMIC_RELAXED,
                                            __HIP_MEMORY_SCOPE_AGENT);
        if (a == n - 1u) {
            __hip_atomic_store(&bar[0], 0u, __ATOMIC_RELAXED,
                               __HIP_MEMORY_SCOPE_AGENT);
            __hip_atomic_store(&bar[1], g + 1u, __ATOMIC_RELAXED,
                               __HIP_MEMORY_SCOPE_AGENT);
        } else {
            while (__hip_atomic_load(&bar[1], __ATOMIC_RELAXED,
                                     __HIP_MEMORY_SCOPE_AGENT) == g)
                __builtin_amdgcn_s_sleep(1);
        }
    }
    __syncthreads();
}

// ---- stage a 64 KB column panel (512-thread blocks, linear) ----------------
__device__ __forceinline__ void stage_cols(const char* src, char* clds,
                                           int tid, int w) {
    #pragma unroll
    for (int k = 0; k < 8; k++)
        GLD_LDS16(src + k * 8192 + (size_t)tid * 16, &clds[k * 8192 + w * 1024]);
}

// barrier + overlapped staging for the next pass (block-local LDS, safe)
__device__ __forceinline__ void gsync_stage(unsigned* bar, unsigned n,
                                            const char* src, char* clds,
                                            int tid, int w) {
    __syncthreads();
    if (src) stage_cols(src, clds, tid, w);
    if (tid == 0) {
        unsigned g = __hip_atomic_load(&bar[1], __ATOMIC_RELAXED,
                                       __HIP_MEMORY_SCOPE_AGENT);
        unsigned a = __hip_atomic_fetch_add(&bar[0], 1u, __ATOMIC_RELAXED,
                                            __HIP_MEMORY_SCOPE_AGENT);
        if (a == n - 1u) {
            __hip_atomic_store(&bar[0], 0u, __ATOMIC_RELAXED,
                               __HIP_MEMORY_SCOPE_AGENT);
            __hip_atomic_store(&bar[1], g + 1u, __ATOMIC_RELAXED,
                               __HIP_MEMORY_SCOPE_AGENT);
        } else {
            while (__hip_atomic_load(&bar[1], __ATOMIC_RELAXED,
                                     __HIP_MEMORY_SCOPE_AGENT) == g)
                __builtin_amdgcn_s_sleep(1);
        }
    }
    __syncthreads();
}

// ---- setup: sums of a and b + zero all barrier lines -----------------------
__global__ void sums_kernel(const float* __restrict__ a, const float* __restrict__ b,
                            float* __restrict__ sums, unsigned* __restrict__ barr) {
    __shared__ float red[32];
    int tid = threadIdx.x;
    if (tid < 1024) barr[tid] = 0u;        // 32 groups x 32 u32 lines
    float pa = 0.f, pb = 0.f;
    for (int i = tid; i < NR; i += blockDim.x) { pa += a[i]; pb += b[i]; }
    pa = wave_reduce_sum(pa);
    pb = wave_reduce_sum(pb);
    int wid = tid >> 6, ln = tid & 63;
    if (ln == 0) { red[wid] = pa; red[wid + 16] = pb; }
    __syncthreads();
    if (tid == 0) {
        float sa = 0.f, sb = 0.f;
        int nw = blockDim.x >> 6;
        for (int w = 0; w < nw; w++) { sa += red[w]; sb += red[w + 16]; }
        sums[0] = logf(sa); sums[1] = logf(sb); sums[2] = sa; sums[3] = sb;
    }
}

// ---- setup: bf16 stream-layout copies, norms, weights, initial partials ----
__global__ void prep_kernel(const float* __restrict__ x, const float* __restrict__ y,
                            const float* __restrict__ a, const float* __restrict__ b,
                            const float* __restrict__ sums,
                            short8* __restrict__ xs, short8* __restrict__ ys,
                            float* __restrict__ x2, float* __restrict__ y2,
                            float* __restrict__ la2, float* __restrict__ lb2,
                            float2* __restrict__ Pb1) {  // initial g-partials
    int gid = blockIdx.x * 256 + threadIdx.x;
    bool isx = gid < NR * 8;
    int cid = isx ? gid : gid - NR * 8;
    int row = cid >> 3;
    int c   = cid & 7;
    const float4* src = (const float4*)(isx ? x : y);
    float4 v0 = src[row * 16 + c * 2];
    float4 v1 = src[row * 16 + c * 2 + 1];

    const float sc = isx ? S2 : 1.0f;
    short8 st;
    st[0] = __bfloat16_as_short(__float2bfloat16(v0.x * sc));
    st[1] = __bfloat16_as_short(__float2bfloat16(v0.y * sc));
    st[2] = __bfloat16_as_short(__float2bfloat16(v0.z * sc));
    st[3] = __bfloat16_as_short(__float2bfloat16(v0.w * sc));
    st[4] = __bfloat16_as_short(__float2bfloat16(v1.x * sc));
    st[5] = __bfloat16_as_short(__float2bfloat16(v1.y * sc));
    st[6] = __bfloat16_as_short(__float2bfloat16(v1.z * sc));
    st[7] = __bfloat16_as_short(__float2bfloat16(v1.w * sc));

    int T = row >> 4, ln = row & 15, f = c >> 2, q = c & 3;
    (isx ? xs : ys)[T * 128 + f * 64 + q * 16 + ln] = st;    // stream layout

    float sq = v0.x*v0.x + v0.y*v0.y + v0.z*v0.z + v0.w*v0.w
             + v1.x*v1.x + v1.y*v1.y + v1.z*v1.z + v1.w*v1.w;
    #pragma unroll
    for (int m = 1; m < 8; m <<= 1) sq += __shfl_xor(sq, m, 64);

    if (c == 0) {
        if (isx) {
            x2[row] = sq;
            la2[row] = (logf(a[row]) - sums[0]) * LOG2E;
        } else {
            y2[row] = sq;
            lb2[row] = (logf(b[row]) - sums[1]) * LOG2E;
            Pb1[row] = make_float2(sq * (LOG2E / EPS), 1.0f);  // g = 0 initially
            #pragma unroll
            for (int k = 1; k < NSPLIT; k++)
                Pb1[k * NR + row] = make_float2(NEGINF, 0.0f);
        }
    }
}

// acc already IS z (bias folded into MFMA C-operand, S2 folded into data).
#define LSE4(acc, mm, ss)                                                \
    {                                                                    \
        float z0 = (acc)[0], z1 = (acc)[1];                              \
        float z2 = (acc)[2], z3 = (acc)[3];                              \
        float mn = fmaxf(fmaxf(fmaxf(z0, z1), fmaxf(z2, z3)), (mm));     \
        float e  = __builtin_amdgcn_exp2f((mm) - mn);                    \
        float p  = (__builtin_amdgcn_exp2f(z0 - mn)                      \
                  + __builtin_amdgcn_exp2f(z1 - mn))                     \
                 + (__builtin_amdgcn_exp2f(z2 - mn)                      \
                  + __builtin_amdgcn_exp2f(z3 - mn));                    \
        (ss) = fmaf((ss), e, p);                                         \
        (mm) = mn;                                                       \
    }

// =================== variant 1: R18 both-resident, 1024 thr =================
__device__ __forceinline__ void do_pass_b(
        const u64* Pin, const float* lw, u64* Pout,
        int colbase, int outidx, int roff, int coff,
        char* mlds, float* cbl, float2 (*comb)[3]) {
    const int tid = threadIdx.x;
    const int w   = tid >> 6, lane = tid & 63;
    const int quad = lane >> 4, ln = lane & 15;
    const int cst = w & 1, rq = w >> 1;

    if (tid < 512) {
        int jj = colbase + tid;
        cbl[tid] = lw[jj] - merge16_a(Pin, jj);
    }
    __syncthreads();

    short8 rf0[4], rf1[4];
    {
        const char* rw = &mlds[roff + rq * 8192];
        #pragma unroll
        for (int t = 0; t < 4; t++) {
            rf0[t] = *(const short8*)(rw + t * 2048 + lane * 16);
            rf1[t] = *(const short8*)(rw + t * 2048 + 1024 + lane * 16);
        }
    }

    float lm[4], ls[4];
    #pragma unroll
    for (int t = 0; t < 4; t++) { lm[t] = NEGINF; ls[t] = 0.f; }

    const char* cw = &mlds[coff + cst * 32768];
    const float* cbw = cbl + cst * 256;
    #pragma unroll 4
    for (int u = 0; u < 16; u++) {
        short8 ya0 = *(const short8*)(cw + u * 2048 + lane * 16);
        short8 ya1 = *(const short8*)(cw + u * 2048 + 1024 + lane * 16);
        float4v cin = *(const float4v*)(cbw + u * 16 + quad * 4);
        #pragma unroll
        for (int tt = 0; tt < 4; tt++) {
            float4v acc = __builtin_amdgcn_mfma_f32_16x16x32_bf16(ya0, rf0[tt], cin, 0, 0, 0);
            acc = __builtin_amdgcn_mfma_f32_16x16x32_bf16(ya1, rf1[tt], acc, 0, 0, 0);
            LSE4(acc, lm[tt], ls[tt]);
        }
    }

    #pragma unroll
    for (int mask = 16; mask < 64; mask <<= 1) {
        #pragma unroll
        for (int t = 0; t < 4; t++) {
            float mo = __shfl_xor(lm[t], mask, 64);
            float so = __shfl_xor(ls[t], mask, 64);
            float M  = fmaxf(lm[t], mo);
            ls[t] = ls[t] * __builtin_amdgcn_exp2f(lm[t] - M)
                  + so    * __builtin_amdgcn_exp2f(mo    - M);
            lm[t] = M;
        }
    }

    __syncthreads();
    if (lane < 16) {
        #pragma unroll
        for (int t = 0; t < 4; t++)
            comb[rq * 64 + t * 16 + ln][cst] = make_float2(lm[t], ls[t]);
    }
    __syncthreads();

    if (tid < 512) {
        float2 c0 = comb[tid][0], c1 = comb[tid][1];
        float M = fmaxf(c0.x, c1.x);
        float S = c0.y * __builtin_amdgcn_exp2f(c0.x - M)
                + c1.y * __builtin_amdgcn_exp2f(c1.x - M);
        st_f2a(Pout + outidx + tid, make_float2(M, S));
    }
}

__global__ __launch_bounds__(1024, 4) void sink_kernel1(
        const short8* __restrict__ xs, const short8* __restrict__ ys,
        const float* __restrict__ la2, const float* __restrict__ lb2,
        u64* P, const float* __restrict__ a, const float* __restrict__ b,
        const float* __restrict__ x2, const float* __restrict__ y2,
        u64* red2, const float* __restrict__ sums,
        unsigned* barr, float* out) {
    __shared__ __attribute__((aligned(16))) char mlds[131072];  // X | Y
    __shared__ __attribute__((aligned(16))) float cbl[512];
    __shared__ float2 comb[512][3];

    const int tid = threadIdx.x;
    const int bi  = blockIdx.x;
    const int ib  = bi >> 4, jb = bi & 15;

    u64* Pf[2] = { P,           P + PSZ };
    u64* Pb[2] = { P + 2 * PSZ, P + 3 * PSZ };
    u64* Pff   = P;
    u64* Pgf   = P + 2 * PSZ;
    unsigned* rbar = barr + ib * 32;
    unsigned* cbar = barr + (16 + jb) * 32;

    const int w = tid >> 6;
    const char* xsrc = (const char*)xs + (size_t)(ib * 512) * 128;
    const char* ysrc = (const char*)ys + (size_t)(jb * 512) * 128;
    #pragma unroll
    for (int r = 0; r < 4; r++) {
        GLD_LDS16(xsrc + r * 16384 + tid * 16, &mlds[r * 16384 + w * 1024]);
        GLD_LDS16(ysrc + r * 16384 + tid * 16, &mlds[65536 + r * 16384 + w * 1024]);
    }

    for (int t = 0; t < N_ITERS; t++) {
        const int par = t & 1;
        do_pass_b(Pb[par ^ 1], lb2, Pf[par],
                  512 * jb, jb * NR + 512 * ib, 0, 65536, mlds, cbl, comb);
        gsync_n(rbar, 16);
        do_pass_b(Pf[par], la2, Pb[par],
                  512 * ib, ib * NR + 512 * jb, 65536, 0, mlds, cbl, comb);
        gsync_n(cbar, 16);
    }

    do_pass_b(Pb[1], lb2, Pff, 512 * jb, jb * NR + 512 * ib, 0, 65536,
              mlds, cbl, comb);
    do_pass_b(Pf[1], la2, Pgf, 512 * ib, ib * NR + 512 * jb, 65536, 0,
              mlds, cbl, comb);
    gsync_n(rbar, 16);
    gsync_n(cbar, 16);

    if (bi < 64 && tid < 256) {
        int r = bi * 128 + (tid & 127);
        bool gsd = tid >= 128;
        float L  = merge16_a(gsd ? Pgf : Pff, r);
        float sq = gsd ? y2[r] : x2[r];
        float wv = gsd ? b[r]  : a[r];
        float v  = wv * (sq - EPSLN2 * L);
        v = wave_reduce_sum(v);
        if ((tid & 63) == 0) cbl[tid >> 6] = v;
    }
    __syncthreads();
    if (bi < 64 && tid == 0)
        st_f2a(red2 + bi, make_float2(cbl[0] + cbl[1], cbl[2] + cbl[3]));
    gsync_n(rbar, 16);
    gsync_n(cbar, 16);

    if (bi == 0 && tid < 64) {
        float2 v = ld_f2a(red2 + tid);
        float da = wave_reduce_sum(v.x);
        float db = wave_reduce_sum(v.y);
        if (tid == 0) out[0] = da / sums[2] + db / sums[3];
    }
}

// =================== variant 2: 2 blocks/CU, streamed cols, 512 thr =========
__device__ __forceinline__ void do_pass_s(
        const u64* Pin, const float* lw, u64* Pout,
        int colbase, const char* rowsrc, char* clds, float* cbl) {
    const int tid = threadIdx.x;
    const int w = tid >> 6, lane = tid & 63;
    const int quad = lane >> 4, ln = lane & 15;

    short8 rf0[2], rf1[2];
    const char* rsrc = rowsrc + (size_t)(w * 2) * 2048 + (size_t)lane * 16;
    #pragma unroll
    for (int t = 0; t < 2; t++) {
        rf0[t] = *(const short8*)(rsrc + t * 2048);
        rf1[t] = *(const short8*)(rsrc + t * 2048 + 1024);
    }

    {
        int j = colbase + tid;
        cbl[tid] = lw[j] - merge16_a(Pin, j);
    }
    __syncthreads();   // drains col staging (vmcnt) + cbl writes

    float lm[2] = { NEGINF, NEGINF }, ls[2] = { 0.f, 0.f };
    #pragma unroll 4
    for (int u = 0; u < 32; u++) {
        short8 ya0 = *(const short8*)(clds + u * 2048 + lane * 16);
        short8 ya1 = *(const short8*)(clds + u * 2048 + 1024 + lane * 16);
        float4v cin = *(const float4v*)(cbl + u * 16 + quad * 4);
        #pragma unroll
        for (int tt = 0; tt < 2; tt++) {
            float4v acc = __builtin_amdgcn_mfma_f32_16x16x32_bf16(ya0, rf0[tt], cin, 0, 0, 0);
            acc = __builtin_amdgcn_mfma_f32_16x16x32_bf16(ya1, rf1[tt], acc, 0, 0, 0);
            LSE4(acc, lm[tt], ls[tt]);
        }
    }

    #pragma unroll
    for (int mask = 16; mask < 64; mask <<= 1) {
        #pragma unroll
        for (int t = 0; t < 2; t++) {
            float mo = __shfl_xor(lm[t], mask, 64);
            float so = __shfl_xor(ls[t], mask, 64);
            float M  = fmaxf(lm[t], mo);
            ls[t] = ls[t] * __builtin_amdgcn_exp2f(lm[t] - M)
                  + so    * __builtin_amdgcn_exp2f(mo    - M);
            lm[t] = M;
        }
    }
    if (lane < 16) {
        #pragma unroll
        for (int t = 0; t < 2; t++)
            st_f2a(Pout + w * 32 + t * 16 + ln, make_float2(lm[t], ls[t]));
    }
}

__global__ __launch_bounds__(512, 4) void sink_kernel2(
        const short8* __restrict__ xs, const short8* __restrict__ ys,
        const float* __restrict__ la2, const float* __restrict__ lb2,
        u64* P, const float* __restrict__ a, const float* __restrict__ b,
        const float* __restrict__ x2, const float* __restrict__ y2,
        u64* red2, const float* __restrict__ sums,
        unsigned* barr, float* out) {
    __shared__ __attribute__((aligned(16))) char clds[65536];
    __shared__ __attribute__((aligned(16))) float cbl[512];

    const int tid = threadIdx.x;
    const int bi  = blockIdx.x;
    const int rb  = bi >> 4;             // 0..31  X-row slice (f)
    const int jb  = bi & 15;             // 0..15  Y-col split (f)
    const int w   = tid >> 6;
    const int rgY = 2 * jb + (rb & 1);   // g-pass Y-row slice

    u64* Pf[2] = { P,           P + PSZ };
    u64* Pb[2] = { P + 2 * PSZ, P + 3 * PSZ };
    u64* Pff   = P;
    u64* Pgf   = P + 2 * PSZ;
    unsigned* rbar = barr + (rb >> 1) * 32;
    unsigned* cbar = barr + (16 + jb) * 32;

    const char* xs_c = (const char*)xs;
    const char* ys_c = (const char*)ys;
    const char* fcol = ys_c + (size_t)jb * 65536;
    const char* gcol = xs_c + (size_t)(rb >> 1) * 65536;
    const char* frow = xs_c + (size_t)rb * 32768;
    const char* grow = ys_c + (size_t)rgY * 32768;

    stage_cols(fcol, clds, tid, w);

    for (int t = 0; t < N_ITERS; t++) {
        const int par = t & 1;
        do_pass_s(Pb[par ^ 1], lb2, Pf[par] + jb * NR + 256 * rb,
                  512 * jb, frow, clds, cbl);
        gsync_stage(rbar, 32, gcol, clds, tid, w);
        do_pass_s(Pf[par], la2, Pb[par] + (rb >> 1) * NR + 256 * rgY,
                  512 * (rb >> 1), grow, clds, cbl);
        gsync_stage(cbar, 32, fcol, clds, tid, w);
    }

    do_pass_s(Pb[1], lb2, Pff + jb * NR + 256 * rb, 512 * jb, frow, clds, cbl);
    __syncthreads();
    stage_cols(gcol, clds, tid, w);
    do_pass_s(Pf[1], la2, Pgf + (rb >> 1) * NR + 256 * rgY,
              512 * (rb >> 1), grow, clds, cbl);

    gsync_stage(rbar, 32, nullptr, clds, tid, w);   // grid-equivalent sync
    gsync_stage(cbar, 32, nullptr, clds, tid, w);

    if (bi < 64 && tid < 256) {
        int r = bi * 128 + (tid & 127);
        bool gsd = tid >= 128;
        float L  = merge16_a(gsd ? Pgf : Pff, r);
        float sq = gsd ? y2[r] : x2[r];
        float wv = gsd ? b[r]  : a[r];
        float v  = wv * (sq - EPSLN2 * L);
        v = wave_reduce_sum(v);
        if ((tid & 63) == 0) cbl[tid >> 6] = v;
    }
    __syncthreads();
    if (bi < 64 && tid == 0)
        st_f2a(red2 + bi, make_float2(cbl[0] + cbl[1], cbl[2] + cbl[3]));
    gsync_stage(rbar, 32, nullptr, clds, tid, w);
    gsync_stage(cbar, 32, nullptr, clds, tid, w);

    if (bi == 0 && tid < 64) {
        float2 v = ld_f2a(red2 + tid);
        float da = wave_reduce_sum(v.x);
        float db = wave_reduce_sum(v.y);
        if (tid == 0) out[0] = da / sums[2] + db / sums[3];
    }
}

extern "C" void kernel_launch(void* const* d_in, const int* in_sizes, int n_in,
                              void* d_out, int out_size, void* d_ws, size_t ws_size,
                              hipStream_t stream) {
    const float* a = (const float*)d_in[0];
    const float* x = (const float*)d_in[1];
    const float* b = (const float*)d_in[2];
    const float* y = (const float*)d_in[3];

    char* ws = (char*)d_ws;
    short8* xs = (short8*)ws;                        // 1 MB stream layout
    short8* ys = (short8*)(ws + (1 << 20));          // 1 MB
    float* fp  = (float*)(ws + (2 << 20));
    float* x2  = fp;
    float* y2  = fp + NR;
    float* la2 = fp + 2 * NR;
    float* lb2 = fp + 3 * NR;
    u64* P     = (u64*)(fp + 4 * NR);                // 4 arrays x 1 MB
    u64* red2  = P + 4 * PSZ;                        // 64 entries
    float* sums  = (float*)(red2 + 64);              // 4 floats
    unsigned* barr = (unsigned*)(ws + (7 << 20));    // 32 lines x 128 B
    float* outp  = (float*)d_out;

    sums_kernel<<<1, 1024, 0, stream>>>(a, b, sums, barr);
    prep_kernel<<<(2 * NR * 8) / 256, 256, 0, stream>>>(x, y, a, b, sums,
                                                        xs, ys,
                                                        x2, y2, la2, lb2,
                                                        (float2*)(P + 3 * PSZ));

    void* args[] = { (void*)&xs, (void*)&ys, (void*)&la2, (void*)&lb2,
                     (void*)&P, (void*)&a, (void*)&b, (void*)&x2, (void*)&y2,
                     (void*)&red2, (void*)&sums, (void*)&barr, (void*)&outp };

    // occupancy-guarded dispatch: sink2 needs 2 blocks/CU co-resident (512
    // blocks cooperative). If the runtime says it can't, use the proven
    // 256-block both-resident kernel instead.
    int nb2 = 0;
    hipError_t qe = hipOccupancyMaxActiveBlocksPerMultiprocessor(
        &nb2, (const void*)sink_kernel2, 512, 0);
    if (qe == hipSuccess && nb2 >= 2) {
        hipLaunchCooperativeKernel((void*)sink_kernel2, dim3(512), dim3(512),
                                   args, 0, stream);
    } else {
        hipLaunchCooperativeKernel((void*)sink_kernel1, dim3(256), dim3(1024),
                                   args, 0, stream);
    }
}